// Round 9
// baseline (9270.788 us; speedup 1.0000x reference)
//
#include <hip/hip_runtime.h>
#include <hip/hip_bf16.h>

#define DEVI __device__ __forceinline__

static constexpr int S = 2048;
static constexpr int B = 64;
static constexpr int M = S * B; // 131072

typedef __attribute__((ext_vector_type(8))) short bf16x8;
typedef __attribute__((ext_vector_type(4))) float f32x4;

DEVI float sigm(float x)   { return 1.0f / (1.0f + __expf(-x)); }
DEVI float tanh_f(float x) { return 1.0f - 2.0f / (1.0f + __expf(2.0f * x)); }

DEVI float ld1(const float* p) { return *p; }
DEVI float ld1(const __hip_bfloat16* p) { return __bfloat162float(*p); }
DEVI void  st1(float* p, float v) { *p = v; }
DEVI void  st1(__hip_bfloat16* p, float v) { *p = __float2bfloat16(v); }

DEVI float4 ld4(const float* p) { return *(const float4*)p; }
DEVI float4 ld4(const __hip_bfloat16* p) {
    const ushort4 u = *(const ushort4*)p;   // 8B-aligned: k%4==0, K%4==0
    union { unsigned int i; float f; } a, b, c, d;
    a.i = (unsigned)u.x << 16; b.i = (unsigned)u.y << 16;
    c.i = (unsigned)u.z << 16; d.i = (unsigned)u.w << 16;
    return make_float4(a.f, b.f, c.f, d.f);
}

DEVI unsigned short f2bf(float v) { __hip_bfloat16 h = __float2bfloat16(v); return *(unsigned short*)&h; }

DEVI float bcastf(float v, int lane) {     // uniform broadcast from lane (v_readlane)
    return __int_as_float(__builtin_amdgcn_readlane(__float_as_int(v), lane));
}
DEVI float shflf(float v, int lane) { return __shfl(v, lane, 64); }

// ---------------------------------------------------------------------------
// zero the stats scratch (4 layers x 1024 floats)
// ---------------------------------------------------------------------------
__global__ void zero_stats(float* stats) {
    stats[blockIdx.x * 256 + threadIdx.x] = 0.f;
}

// ---------------------------------------------------------------------------
// xW projection GEMM (bf16 MFMA, fp32 accum), one direction, one time window.
//   Xo[m][n] = sum_k Anorm(m,k)*W(n,k) + bih[n] + bhh[n],  n < N (= 4H)
// Window row m: b = m & 63, s = t0 + (m >> 6).
//   mode==0 -> A = raw x [B,S,7] (K=7, scalar-staged, k-guarded)
//   mode==1 -> A = act [M,K], normalized on the fly: a*scg[k]+sb[k] (K%32==0)
// Tile: BM=128, BN=128, BK=32; 256 thr = 4 waves (2x2), 64x64 per wave,
// mfma_f32_16x16x32_bf16 fragments; A/B staged in LDS as bf16, padded rows.
// ---------------------------------------------------------------------------
template<typename XT, typename AT>
__global__ __launch_bounds__(256) void gemm_mfma(
    const AT* __restrict__ A, const float* __restrict__ W,
    const float* __restrict__ bih, const float* __restrict__ bhh,
    const float* __restrict__ scg_sb, XT* __restrict__ Xo,
    int K, int N, int mode, int t0)
{
    __shared__ __align__(16) unsigned short As[128][40];  // [row][k] bf16, pad 32->40
    __shared__ __align__(16) unsigned short Bs[128][40];
    const int tid = threadIdx.x;
    const int m0 = blockIdx.x * 128;
    const int n0 = blockIdx.y * 128;
    const int l  = tid & 63, wid = tid >> 6;
    const int wm = wid >> 1, wn = wid & 1;

    f32x4 acc[4][4];
#pragma unroll
    for (int fm = 0; fm < 4; ++fm)
#pragma unroll
        for (int fn = 0; fn < 4; ++fn) acc[fm][fn] = (f32x4){0.f, 0.f, 0.f, 0.f};

    const int nks = (K + 31) / 32;
    for (int ks = 0; ks < nks; ++ks) {
        const int kc = ks * 32;
        // ---- stage A tile [128][32]
        if (mode == 1) {
#pragma unroll
            for (int it = 0; it < 4; ++it) {
                const int idx = it * 256 + tid;          // 1024 float4 groups
                const int row = idx >> 3, k4 = (idx & 7) * 4;
                const int m = m0 + row;
                const size_t ma = (size_t)(t0 + (m >> 6)) * 64 + (m & 63);
                const float4 a4 = ld4(A + ma * K + kc + k4);
                const float4 g4 = *(const float4*)(scg_sb + kc + k4);
                const float4 b4 = *(const float4*)(scg_sb + K + kc + k4);
                ushort4 u;
                u.x = f2bf(a4.x * g4.x + b4.x); u.y = f2bf(a4.y * g4.y + b4.y);
                u.z = f2bf(a4.z * g4.z + b4.z); u.w = f2bf(a4.w * g4.w + b4.w);
                *(ushort4*)&As[row][k4] = u;
            }
        } else {  // K==7 raw input
#pragma unroll
            for (int it = 0; it < 16; ++it) {
                const int idx = it * 256 + tid;
                const int row = idx >> 5, kk = idx & 31;
                const int m = m0 + row;
                float v = 0.f;
                if (kk < K)
                    v = ld1(A + ((size_t)(m & 63) * S + (t0 + (m >> 6))) * K + kk);
                As[row][kk] = f2bf(v);
            }
        }
        // ---- stage B tile: Bs[n][k] = W[n0+n][kc+k], zero outside N/K
        if (!(K & 3)) {
#pragma unroll
            for (int it = 0; it < 4; ++it) {
                const int idx = it * 256 + tid;
                const int row = idx >> 3, k4 = (idx & 7) * 4;
                const int n = n0 + row;
                float4 w4 = make_float4(0.f, 0.f, 0.f, 0.f);
                if (n < N) w4 = *(const float4*)(W + (size_t)n * K + kc + k4);
                ushort4 u;
                u.x = f2bf(w4.x); u.y = f2bf(w4.y); u.z = f2bf(w4.z); u.w = f2bf(w4.w);
                *(ushort4*)&Bs[row][k4] = u;
            }
        } else {
#pragma unroll
            for (int it = 0; it < 16; ++it) {
                const int idx = it * 256 + tid;
                const int row = idx >> 5, kk = idx & 31;
                const int n = n0 + row;
                float v = 0.f;
                if (n < N && kk < K) v = W[(size_t)n * K + kk];
                Bs[row][kk] = f2bf(v);
            }
        }
        __syncthreads();
        // ---- fragments + MFMA
        bf16x8 af[4], bw[4];
#pragma unroll
        for (int f = 0; f < 4; ++f) {
            af[f] = *(const bf16x8*)&As[wm * 64 + f * 16 + (l & 15)][(l >> 4) * 8];
            bw[f] = *(const bf16x8*)&Bs[wn * 64 + f * 16 + (l & 15)][(l >> 4) * 8];
        }
#pragma unroll
        for (int fm = 0; fm < 4; ++fm)
#pragma unroll
            for (int fn = 0; fn < 4; ++fn)
                acc[fm][fn] = __builtin_amdgcn_mfma_f32_16x16x32_bf16(af[fm], bw[fn], acc[fm][fn], 0, 0, 0);
        __syncthreads();
    }
    // ---- epilogue: D col = lane&15, row = (lane>>4)*4 + r  [m89/m91 layout]
#pragma unroll
    for (int fn = 0; fn < 4; ++fn) {
        const int n = n0 + wn * 64 + fn * 16 + (l & 15);
        if (n < N) {
            const float bias = bih[n] + bhh[n];
#pragma unroll
            for (int fm = 0; fm < 4; ++fm) {
                const int mr = m0 + wm * 64 + fm * 16 + (l >> 4) * 4;
#pragma unroll
                for (int r = 0; r < 4; ++r)
                    st1(Xo + (size_t)(mr + r) * N + n, acc[fm][fn][r] + bias);
            }
        }
    }
}

// ---------------------------------------------------------------------------
// H=16 scan: ONE wave per chain, no LDS, no barriers, NO gate shuffles.
// Every lane computes ALL FOUR gates of unit u = j&15 (4 independent 16-FMA
// chains); h broadcast via v_readlane from lanes 0-15 (lane k holds h[k]).
// ---------------------------------------------------------------------------
template<int PF, typename XT, typename AT>
__global__ __launch_bounds__(64, 1) void lstm_scan16(
    const XT* __restrict__ Xf, const XT* __restrict__ Xb_,
    AT* __restrict__ act, const float* __restrict__ whh,
    float* __restrict__ stats, float* __restrict__ state,
    int t0f, int tb_out, int CS, int first)
{
    const int j = threadIdx.x;
    const int dir = (blockIdx.x >= 64) ? 1 : 0;
    const int b = blockIdx.x & 63;
    const int u = j & 15;

    float wi[16], wf_[16], wg[16], wo[16];
#pragma unroll
    for (int k = 0; k < 16; ++k) {
        wi[k]  = whh[(size_t)(dir * 64 +      u) * 16 + k];
        wf_[k] = whh[(size_t)(dir * 64 + 16 + u) * 16 + k];
        wg[k]  = whh[(size_t)(dir * 64 + 32 + u) * 16 + k];
        wo[k]  = whh[(size_t)(dir * 64 + 48 + u) * 16 + k];
    }

    const int sbase = (dir * 64 + b) * 32;
    float hv = 0.f, cc = 0.f, s1 = 0.f, s2 = 0.f;
    if (!first) { hv = state[sbase + u]; cc = state[sbase + 16 + u]; }

    const XT* Xd = (dir ? Xb_ : Xf) + (size_t)b * 64 + u;
    const size_t rstride = (size_t)64 * 64;
    float xw[PF][4];
#pragma unroll
    for (int p = 0; p < PF; ++p) {
        const size_t ro = (size_t)(dir ? (CS - 1 - p) : p) * rstride;
        xw[p][0] = ld1(Xd + ro);      xw[p][1] = ld1(Xd + ro + 16);
        xw[p][2] = ld1(Xd + ro + 32); xw[p][3] = ld1(Xd + ro + 48);
    }

    for (int tb = 0; tb < CS; tb += PF) {
#pragma unroll
        for (int p = 0; p < PF; ++p) {
            const int pstep = tb + p;
            float gi = xw[p][0], gf = xw[p][1], gg = xw[p][2], go = xw[p][3];
#pragma unroll
            for (int k = 0; k < 16; ++k) {
                const float s = bcastf(hv, k);
                gi += s * wi[k]; gf += s * wf_[k]; gg += s * wg[k]; go += s * wo[k];
            }
            if (pstep + PF < CS) {
                const size_t ro = (size_t)(dir ? (CS - 1 - (pstep + PF)) : (pstep + PF)) * rstride;
                xw[p][0] = ld1(Xd + ro);      xw[p][1] = ld1(Xd + ro + 16);
                xw[p][2] = ld1(Xd + ro + 32); xw[p][3] = ld1(Xd + ro + 48);
            }
            cc = sigm(gf) * cc + sigm(gi) * tanh_f(gg);
            hv = sigm(go) * tanh_f(cc);
            if (j < 16) {
                AT hq; st1(&hq, hv);
                const float hs = ld1(&hq);
                const int tt = dir ? (tb_out - pstep) : (t0f + pstep);
                act[((size_t)tt * B + b) * 32 + dir * 16 + j] = hq;
                s1 += hs; s2 += hs * hs;
            }
        }
    }
    if (j < 16) {
        state[sbase + j] = hv;
        state[sbase + 16 + j] = cc;
        atomicAdd(stats + dir * 16 + j, s1);
        atomicAdd(stats + 32 + dir * 16 + j, s2);
    }
}

// ---------------------------------------------------------------------------
// H=32 scan: ONE wave per chain. Lane j owns gate rows j (i/f) and 64+j (g/o).
// Unit u=j&31: i_u=lane u.rowA, f_u=lane(u+32).rowA, g_u=lane u.rowB,
// o_u=lane(u+32).rowB. h broadcast via readlane from lanes 0-31.
// ---------------------------------------------------------------------------
template<int PF, typename XT, typename AT>
__global__ __launch_bounds__(64, 1) void lstm_scan32(
    const XT* __restrict__ Xf, const XT* __restrict__ Xb_,
    AT* __restrict__ act, const float* __restrict__ whh,
    float* __restrict__ stats, float* __restrict__ state,
    int t0f, int tb_out, int CS, int first)
{
    const int j = threadIdx.x;
    const int dir = (blockIdx.x >= 64) ? 1 : 0;
    const int b = blockIdx.x & 63;
    const int u = j & 31;

    float w0[32], w1[32];
#pragma unroll
    for (int k = 0; k < 32; ++k) {
        w0[k] = whh[(size_t)(dir * 128 + j) * 32 + k];
        w1[k] = whh[(size_t)(dir * 128 + 64 + j) * 32 + k];
    }

    const int sbase = (dir * 64 + b) * 64;
    float hv = 0.f, cc = 0.f, s1 = 0.f, s2 = 0.f;
    if (!first) { hv = state[sbase + u]; cc = state[sbase + 32 + u]; }

    const XT* Xd = (dir ? Xb_ : Xf) + (size_t)b * 128 + j;
    const size_t rstride = (size_t)64 * 128;
    float xwA[PF], xwB[PF];
#pragma unroll
    for (int p = 0; p < PF; ++p) {
        const size_t ro = (size_t)(dir ? (CS - 1 - p) : p) * rstride;
        xwA[p] = ld1(Xd + ro); xwB[p] = ld1(Xd + ro + 64);
    }

    for (int tb = 0; tb < CS; tb += PF) {
#pragma unroll
        for (int p = 0; p < PF; ++p) {
            const int pstep = tb + p;
            float gA = xwA[p], gB = xwB[p];
#pragma unroll
            for (int k = 0; k < 32; ++k) {
                const float s = bcastf(hv, k);
                gA += s * w0[k]; gB += s * w1[k];
            }
            if (pstep + PF < CS) {
                const size_t ro = (size_t)(dir ? (CS - 1 - (pstep + PF)) : (pstep + PF)) * rstride;
                xwA[p] = ld1(Xd + ro); xwB[p] = ld1(Xd + ro + 64);
            }
            const float iv = shflf(gA, u);
            const float fv = shflf(gA, u + 32);
            const float gv = shflf(gB, u);
            const float ov = shflf(gB, u + 32);
            cc = sigm(fv) * cc + sigm(iv) * tanh_f(gv);
            hv = sigm(ov) * tanh_f(cc);
            if (j < 32) {
                AT hq; st1(&hq, hv);
                const float hs = ld1(&hq);
                const int tt = dir ? (tb_out - pstep) : (t0f + pstep);
                act[((size_t)tt * B + b) * 64 + dir * 32 + j] = hq;
                s1 += hs; s2 += hs * hs;
            }
        }
    }
    if (j < 32) {
        state[sbase + j] = hv;
        state[sbase + 32 + j] = cc;
        atomicAdd(stats + dir * 32 + j, s1);
        atomicAdd(stats + 64 + dir * 32 + j, s2);
    }
}

// ---------------------------------------------------------------------------
// H=64/128 scan: LDS h broadcast, 2 barriers/step, R=1 row/thread (T = 4H
// threads) -- R=1 keeps per-thread weights at H VGPRs => NO SPILL (the round-6
// H=128 R=2 config needed ~290 VGPRs at 208 allocated and spilled Whh to
// scratch every step; that was the dominant cost of the whole net).
// ---------------------------------------------------------------------------
template<int H, int R, int PF, typename XT, typename AT>
__global__ __launch_bounds__(4 * H / R, 1) void lstm_scan(
    const XT* __restrict__ Xf, const XT* __restrict__ Xb_,
    AT* __restrict__ act, const float* __restrict__ whh,
    float* __restrict__ stats, float* __restrict__ state,
    int t0f, int tb_out, int CS, int first)
{
    constexpr int N4 = 4 * H;
    constexpr int T  = N4 / R;
    constexpr int CO = 2 * H;
    const int j   = threadIdx.x;
    const int dir = (blockIdx.x >= 64) ? 1 : 0;
    const int b   = blockIdx.x & 63;

    __shared__ __align__(16) float h_lds[H];
    __shared__ float g_lds[N4];

    float w[R][H];
#pragma unroll
    for (int r = 0; r < R; ++r)
#pragma unroll
        for (int k = 0; k < H; ++k)
            w[r][k] = whh[((size_t)dir * N4 + j + r * T) * H + k];

    const int sbase = (dir * 64 + b) * 2 * H;
    float cc = 0.f, s1 = 0.f, s2 = 0.f;
    if (j < H) {
        float h0 = 0.f;
        if (!first) { h0 = state[sbase + j]; cc = state[sbase + H + j]; }
        h_lds[j] = h0;
    }
    __syncthreads();

    const XT* Xd = (dir ? Xb_ : Xf) + (size_t)b * N4 + j;
    const size_t rstride = (size_t)64 * N4;

    float xw[PF][R];
#pragma unroll
    for (int p = 0; p < PF; ++p) {
        const int row = dir ? (CS - 1 - p) : p;
#pragma unroll
        for (int r = 0; r < R; ++r)
            xw[p][r] = ld1(Xd + (size_t)row * rstride + r * T);
    }

    for (int tb = 0; tb < CS; tb += PF) {
#pragma unroll
        for (int p = 0; p < PF; ++p) {
            const int pstep = tb + p;
            float acc0[R], acc1[R], acc2[R], acc3[R];
#pragma unroll
            for (int r = 0; r < R; ++r) { acc0[r] = 0.f; acc1[r] = 0.f; acc2[r] = 0.f; acc3[r] = 0.f; }
            const float4* h4 = (const float4*)h_lds;
#pragma unroll
            for (int k4 = 0; k4 < H / 4; ++k4) {
                const float4 hv = h4[k4];
#pragma unroll
                for (int r = 0; r < R; ++r) {
                    acc0[r] += w[r][4 * k4 + 0] * hv.x;
                    acc1[r] += w[r][4 * k4 + 1] * hv.y;
                    acc2[r] += w[r][4 * k4 + 2] * hv.z;
                    acc3[r] += w[r][4 * k4 + 3] * hv.w;
                }
            }
            float g[R];
#pragma unroll
            for (int r = 0; r < R; ++r)
                g[r] = (acc0[r] + acc1[r]) + (acc2[r] + acc3[r]) + xw[p][r];
            if (pstep + PF < CS) {
                const int row = dir ? (CS - 1 - (pstep + PF)) : (pstep + PF);
#pragma unroll
                for (int r = 0; r < R; ++r)
                    xw[p][r] = ld1(Xd + (size_t)row * rstride + r * T);
            }
#pragma unroll
            for (int r = 0; r < R; ++r) g_lds[j + r * T] = g[r];
            __syncthreads();
            if (j < H) {
                const float fi = sigm(g_lds[j]);
                const float ff = sigm(g_lds[H + j]);
                const float fg = tanh_f(g_lds[2 * H + j]);
                const float fo = sigm(g_lds[3 * H + j]);
                cc = ff * cc + fi * fg;
                const float hv = fo * tanh_f(cc);
                h_lds[j] = hv;
                AT hq; st1(&hq, hv);
                const float hs = ld1(&hq);
                const int tt = dir ? (tb_out - pstep) : (t0f + pstep);
                act[((size_t)tt * B + b) * CO + dir * H + j] = hq;
                s1 += hs; s2 += hs * hs;
            }
            __syncthreads();
        }
    }
    if (j < H) {
        state[sbase + j]     = h_lds[j];
        state[sbase + H + j] = cc;
        atomicAdd(stats + dir * H + j, s1);
        atomicAdd(stats + CO + dir * H + j, s2);
    }
}

// ---------------------------------------------------------------------------
// BN finalize: scg = gamma*rsqrt(var+eps), sb = beta - mean*scg
// ---------------------------------------------------------------------------
__global__ void bn_finalize(const float* __restrict__ sums, float* __restrict__ scg_sb,
                            const float* __restrict__ gamma, const float* __restrict__ beta,
                            int CO)
{
    const int c = threadIdx.x;
    if (c < CO) {
        const float inv  = 1.0f / (float)M;
        const float mean = sums[c] * inv;
        const float var  = fmaxf(sums[CO + c] * inv - mean * mean, 0.f);
        const float s    = gamma[c] * rsqrtf(var + 1e-5f);
        scg_sb[c]      = s;
        scg_sb[CO + c] = beta[c] - mean * s;
    }
}

// ---------------------------------------------------------------------------
// Final FC: out[b,s,j] = sum_c bn3(act[s,b,c]) * fc_w[j,c] + fc_b[j], j<11
// ---------------------------------------------------------------------------
template<typename AT>
__global__ __launch_bounds__(256) void fc_kernel(
    const AT* __restrict__ act, const float* __restrict__ scg_sb,
    const float* __restrict__ fc_w, const float* __restrict__ fc_b,
    float* __restrict__ out)
{
    __shared__ __align__(16) float a_s[32][264];
    __shared__ __align__(16) float w_s[11][264];
    const int tid = threadIdx.x;
    const int m0  = blockIdx.x * 32;
#pragma unroll
    for (int u = 0; u < 12; ++u) {
        int q = u * 256 + tid;
        int uu = q >> 8, c = q & 255;
        if (uu < 11) w_s[uu][c] = fc_w[uu * 256 + c];
    }
#pragma unroll
    for (int u = 0; u < 8; ++u) {
        int q = u * 256 + tid;
        int r = q >> 6, c4 = q & 63;
        const float4 a4 = ld4(act + (size_t)(m0 + r) * 256 + c4 * 4);
        const float4 g4 = *(const float4*)(scg_sb + c4 * 4);
        const float4 b4 = *(const float4*)(scg_sb + 256 + c4 * 4);
        float4 v;
        v.x = a4.x * g4.x + b4.x; v.y = a4.y * g4.y + b4.y;
        v.z = a4.z * g4.z + b4.z; v.w = a4.w * g4.w + b4.w;
        *(float4*)&a_s[r][c4 * 4] = v;
    }
    __syncthreads();
    const int r = tid >> 3, jj = tid & 7;
    const size_t m = (size_t)m0 + r;
    float* orow = out + ((m & 63) * S + (m >> 6)) * 11;
#pragma unroll
    for (int jv = 0; jv < 2; ++jv) {
        const int j = jj + jv * 8;
        if (j < 11) {
            float a0 = 0, a1 = 0, a2 = 0, a3 = 0;
#pragma unroll
            for (int c4 = 0; c4 < 64; ++c4) {
                const float4 av = *(const float4*)&a_s[r][c4 * 4];
                const float4 wv = *(const float4*)&w_s[j][c4 * 4];
                a0 += av.x * wv.x; a1 += av.y * wv.y;
                a2 += av.z * wv.z; a3 += av.w * wv.w;
            }
            orow[j] = (a0 + a1) + (a2 + a3) + fc_b[j];
        }
    }
}

// ---------------------------------------------------------------------------
// One bidirectional layer, time-chunked; ping-pong act buffers (no aliasing).
// ---------------------------------------------------------------------------
template<int H, typename XT, typename AT, typename AIN>
static void run_layer(const AIN* A, const float* wih, const float* whh,
                      const float* bih, const float* bhh,
                      const float* scg_prev, AT* act_out,
                      float* stats_l, float* state, XT* Xbuf,
                      int K, int mode, int CS, hipStream_t stream)
{
    const int N4 = 4 * H, P = S / CS;
    const size_t half = (size_t)CS * 64 * N4;
    XT* Xf = Xbuf;
    XT* Xb = Xbuf + half;
    const dim3 gg(CS * 64 / 128, (N4 + 127) / 128);
    for (int jc = 0; jc < P; ++jc) {
        gemm_mfma<XT, AIN><<<gg, 256, 0, stream>>>(
            A, wih, bih, bhh, scg_prev, Xf, K, N4, mode, jc * CS);
        gemm_mfma<XT, AIN><<<gg, 256, 0, stream>>>(
            A, wih + (size_t)N4 * K, bih + N4, bhh + N4, scg_prev, Xb, K, N4, mode, S - (jc + 1) * CS);
        if constexpr (H == 16)
            lstm_scan16<4, XT, AT><<<128, 64, 0, stream>>>(
                Xf, Xb, act_out, whh, stats_l, state, jc * CS, S - 1 - jc * CS, CS, jc == 0);
        else if constexpr (H == 32)
            lstm_scan32<4, XT, AT><<<128, 64, 0, stream>>>(
                Xf, Xb, act_out, whh, stats_l, state, jc * CS, S - 1 - jc * CS, CS, jc == 0);
        else
            lstm_scan<H, 1, 4, XT, AT><<<128, 4 * H, 0, stream>>>(   // R=1: no VGPR spill
                Xf, Xb, act_out, whh, stats_l, state, jc * CS, S - 1 - jc * CS, CS, jc == 0);
    }
}

// ---------------------------------------------------------------------------
// Orchestration (inputs order: x, then per layer wih/whh/bih/bhh/gamma/beta,
// then fc_w/fc_b). ws: stats[4096 f32] | state[32768 f32] | actA | actB | X.
// ---------------------------------------------------------------------------
template<typename XT, typename AT>
static void run_all(void* const* d_in, float* out, float* stats, float* state,
                    AT* actA, AT* actB, XT* Xbuf, const int* CS, hipStream_t stream)
{
    auto in = [&](int i) { return (const float*)d_in[i]; };
    zero_stats<<<16, 256, 0, stream>>>(stats);

    run_layer<16, XT, AT, float>((const float*)d_in[0], in(1), in(2), in(3), in(4),
                                 nullptr, actA, stats + 0, state, Xbuf, 7, 0, CS[0], stream);
    bn_finalize<<<1, 256, 0, stream>>>(stats + 0, stats + 512, in(5), in(6), 32);

    run_layer<32, XT, AT, AT>(actA, in(7), in(8), in(9), in(10),
                              stats + 512, actB, stats + 1024, state, Xbuf, 32, 1, CS[1], stream);
    bn_finalize<<<1, 256, 0, stream>>>(stats + 1024, stats + 1536, in(11), in(12), 64);

    run_layer<64, XT, AT, AT>(actB, in(13), in(14), in(15), in(16),
                              stats + 1536, actA, stats + 2048, state, Xbuf, 64, 1, CS[2], stream);
    bn_finalize<<<1, 256, 0, stream>>>(stats + 2048, stats + 2560, in(17), in(18), 128);

    run_layer<128, XT, AT, AT>(actA, in(19), in(20), in(21), in(22),
                               stats + 2560, actB, stats + 3072, state, Xbuf, 128, 1, CS[3], stream);
    bn_finalize<<<1, 256, 0, stream>>>(stats + 3072, stats + 3584, in(23), in(24), 256);

    fc_kernel<AT><<<M / 32, 256, 0, stream>>>(actB, stats + 3584, in(25), in(26), out);
}

// largest power-of-2 chunk CS in [64, 2048] whose 2-window X fits in xavail
static inline int fit_cs(size_t xavail, size_t bytes_per_step) {
    for (int cs = 2048; cs >= 64; cs >>= 1)
        if ((size_t)cs * bytes_per_step <= xavail) return cs;
    return 64;
}

extern "C" void kernel_launch(void* const* d_in, const int* in_sizes, int n_in,
                              void* d_out, int out_size, void* d_ws, size_t ws_size,
                              hipStream_t stream)
{
    (void)in_sizes; (void)n_in; (void)out_size;
    float* out = (float*)d_out;
    char* ws = (char*)d_ws;
    const size_t STB  = 16384;                 // stats: 4096 f32
    const size_t STT  = 131072;                // state: 2*64*2*128 f32
    const size_t HEAD = STB + STT;
    const size_t AAf  = (size_t)M * 128 * 4;   // actA fp32 (64 MiB)
    const size_t ABf  = (size_t)M * 256 * 4;   // actB fp32 (128 MiB)
    const int H8[4] = {128, 256, 512, 1024};   // both-dir X cols per layer

    float* stats = (float*)ws;
    float* state = (float*)(ws + STB);
    char*  bufs  = ws + HEAD;
    int CS[4];

    if (ws_size >= HEAD + AAf + ABf + (size_t)128 * 64 * 1024 * 4) {
        // Plan A: fp32 storage (X time-chunked as needed)
        float* actA = (float*)bufs;
        float* actB = (float*)(bufs + AAf);
        float* X    = (float*)(bufs + AAf + ABf);
        const size_t xavail = ws_size - HEAD - AAf - ABf;
        for (int l = 0; l < 4; ++l) CS[l] = fit_cs(xavail, (size_t)64 * H8[l] * 4);
        run_all<float, float>(d_in, out, stats, state, actA, actB, X, CS, stream);
    } else if (ws_size >= HEAD + AAf + ABf + (size_t)64 * 64 * 1024 * 2) {
        // Plan B: fp32 act, bf16 X
        float* actA = (float*)bufs;
        float* actB = (float*)(bufs + AAf);
        __hip_bfloat16* X = (__hip_bfloat16*)(bufs + AAf + ABf);
        const size_t xavail = ws_size - HEAD - AAf - ABf;
        for (int l = 0; l < 4; ++l) CS[l] = fit_cs(xavail, (size_t)64 * H8[l] * 2);
        run_all<__hip_bfloat16, float>(d_in, out, stats, state, actA, actB, X, CS, stream);
    } else {
        // Plan C: bf16 act + bf16 X (~105 MiB floor)
        __hip_bfloat16* actA = (__hip_bfloat16*)bufs;
        __hip_bfloat16* actB = (__hip_bfloat16*)(bufs + AAf / 2);
        __hip_bfloat16* X    = (__hip_bfloat16*)(bufs + AAf / 2 + ABf / 2);
        const size_t used = HEAD + AAf / 2 + ABf / 2;
        const size_t xavail = (ws_size > used) ? (ws_size - used) : 0;
        for (int l = 0; l < 4; ++l) CS[l] = fit_cs(xavail, (size_t)64 * H8[l] * 2);
        run_all<__hip_bfloat16, __hip_bfloat16>(d_in, out, stats, state, actA, actB, X, CS, stream);
    }
}

// Round 10
// 9030.728 us; speedup vs baseline: 1.0266x; 1.0266x over previous
//
#include <hip/hip_runtime.h>
#include <hip/hip_bf16.h>

#define DEVI __device__ __forceinline__

static constexpr int S = 2048;
static constexpr int B = 64;
static constexpr int M = S * B; // 131072

typedef __attribute__((ext_vector_type(8))) short bf16x8;
typedef __attribute__((ext_vector_type(4))) float f32x4;

DEVI float sigm(float x)   { return 1.0f / (1.0f + __expf(-x)); }
DEVI float tanh_f(float x) { return 1.0f - 2.0f / (1.0f + __expf(2.0f * x)); }

DEVI float ld1(const float* p) { return *p; }
DEVI float ld1(const __hip_bfloat16* p) { return __bfloat162float(*p); }
DEVI void  st1(float* p, float v) { *p = v; }
DEVI void  st1(__hip_bfloat16* p, float v) { *p = __float2bfloat16(v); }

DEVI float4 ld4(const float* p) { return *(const float4*)p; }
DEVI float4 ld4(const __hip_bfloat16* p) {
    const ushort4 u = *(const ushort4*)p;   // 8B-aligned: k%4==0, K%4==0
    union { unsigned int i; float f; } a, b, c, d;
    a.i = (unsigned)u.x << 16; b.i = (unsigned)u.y << 16;
    c.i = (unsigned)u.z << 16; d.i = (unsigned)u.w << 16;
    return make_float4(a.f, b.f, c.f, d.f);
}

DEVI unsigned short f2bf(float v) { __hip_bfloat16 h = __float2bfloat16(v); return *(unsigned short*)&h; }

DEVI float shflf(float v, int lane) { return __shfl(v, lane, 64); }
DEVI float shflxf(float v, int mask) { return __shfl_xor(v, mask, 64); }

// ---------------------------------------------------------------------------
// zero the stats scratch (4 layers x 1024 floats)
// ---------------------------------------------------------------------------
__global__ void zero_stats(float* stats) {
    stats[blockIdx.x * 256 + threadIdx.x] = 0.f;
}

// ---------------------------------------------------------------------------
// xW projection GEMM (bf16 MFMA, fp32 accum), BOTH directions (blockIdx.z),
// one time window of CS steps per direction.
//   Xo[z][m][n] = sum_k Anorm(m,k)*W[z](n,k) + bih[z][n] + bhh[z][n]
// Window row m: b = m & 63, s = t0z + (m >> 6), t0z = z ? t0b : t0f.
//   mode==0 -> A = raw x [B,S,7] (K=7, scalar-staged, k-guarded)
//   mode==1 -> A = act [M,K], normalized on the fly: a*scg[k]+sb[k] (K%32==0)
// Tile: BM=128, BN=128, BK=32; 256 thr = 4 waves (2x2), 64x64 per wave.
// ---------------------------------------------------------------------------
template<typename XT, typename AT>
__global__ __launch_bounds__(256) void gemm_mfma(
    const AT* __restrict__ A, const float* __restrict__ W,
    const float* __restrict__ bih, const float* __restrict__ bhh,
    const float* __restrict__ scg_sb, XT* __restrict__ Xo,
    int K, int N, int mode, int t0f, int t0b, size_t halfElems)
{
    __shared__ __align__(16) unsigned short As[128][40];  // [row][k] bf16, pad 32->40
    __shared__ __align__(16) unsigned short Bs[128][40];
    const int tid = threadIdx.x;
    const int m0 = blockIdx.x * 128;
    const int n0 = blockIdx.y * 128;
    const int dz = blockIdx.z;
    const int t0 = dz ? t0b : t0f;
    const float* Wd   = W   + (size_t)dz * N * K;
    const float* bihd = bih + (size_t)dz * N;
    const float* bhhd = bhh + (size_t)dz * N;
    XT* Xod = Xo + (size_t)dz * halfElems;
    const int l  = tid & 63, wid = tid >> 6;
    const int wm = wid >> 1, wn = wid & 1;

    f32x4 acc[4][4];
#pragma unroll
    for (int fm = 0; fm < 4; ++fm)
#pragma unroll
        for (int fn = 0; fn < 4; ++fn) acc[fm][fn] = (f32x4){0.f, 0.f, 0.f, 0.f};

    const int nks = (K + 31) / 32;
    for (int ks = 0; ks < nks; ++ks) {
        const int kc = ks * 32;
        // ---- stage A tile [128][32]
        if (mode == 1) {
#pragma unroll
            for (int it = 0; it < 4; ++it) {
                const int idx = it * 256 + tid;          // 1024 float4 groups
                const int row = idx >> 3, k4 = (idx & 7) * 4;
                const int m = m0 + row;
                const size_t ma = (size_t)(t0 + (m >> 6)) * 64 + (m & 63);
                const float4 a4 = ld4(A + ma * K + kc + k4);
                const float4 g4 = *(const float4*)(scg_sb + kc + k4);
                const float4 b4 = *(const float4*)(scg_sb + K + kc + k4);
                ushort4 u;
                u.x = f2bf(a4.x * g4.x + b4.x); u.y = f2bf(a4.y * g4.y + b4.y);
                u.z = f2bf(a4.z * g4.z + b4.z); u.w = f2bf(a4.w * g4.w + b4.w);
                *(ushort4*)&As[row][k4] = u;
            }
        } else {  // K==7 raw input
#pragma unroll
            for (int it = 0; it < 16; ++it) {
                const int idx = it * 256 + tid;
                const int row = idx >> 5, kk = idx & 31;
                const int m = m0 + row;
                float v = 0.f;
                if (kk < K)
                    v = ld1(A + ((size_t)(m & 63) * S + (t0 + (m >> 6))) * K + kk);
                As[row][kk] = f2bf(v);
            }
        }
        // ---- stage B tile: Bs[n][k] = Wd[n0+n][kc+k], zero outside N/K
        if (!(K & 3)) {
#pragma unroll
            for (int it = 0; it < 4; ++it) {
                const int idx = it * 256 + tid;
                const int row = idx >> 3, k4 = (idx & 7) * 4;
                const int n = n0 + row;
                float4 w4 = make_float4(0.f, 0.f, 0.f, 0.f);
                if (n < N) w4 = *(const float4*)(Wd + (size_t)n * K + kc + k4);
                ushort4 u;
                u.x = f2bf(w4.x); u.y = f2bf(w4.y); u.z = f2bf(w4.z); u.w = f2bf(w4.w);
                *(ushort4*)&Bs[row][k4] = u;
            }
        } else {
#pragma unroll
            for (int it = 0; it < 16; ++it) {
                const int idx = it * 256 + tid;
                const int row = idx >> 5, kk = idx & 31;
                const int n = n0 + row;
                float v = 0.f;
                if (n < N && kk < K) v = Wd[(size_t)n * K + kk];
                Bs[row][kk] = f2bf(v);
            }
        }
        __syncthreads();
        // ---- fragments + MFMA
        bf16x8 af[4], bw[4];
#pragma unroll
        for (int f = 0; f < 4; ++f) {
            af[f] = *(const bf16x8*)&As[wm * 64 + f * 16 + (l & 15)][(l >> 4) * 8];
            bw[f] = *(const bf16x8*)&Bs[wn * 64 + f * 16 + (l & 15)][(l >> 4) * 8];
        }
#pragma unroll
        for (int fm = 0; fm < 4; ++fm)
#pragma unroll
            for (int fn = 0; fn < 4; ++fn)
                acc[fm][fn] = __builtin_amdgcn_mfma_f32_16x16x32_bf16(af[fm], bw[fn], acc[fm][fn], 0, 0, 0);
        __syncthreads();
    }
    // ---- epilogue: D col = lane&15, row = (lane>>4)*4 + r  [m89/m91 layout]
#pragma unroll
    for (int fn = 0; fn < 4; ++fn) {
        const int n = n0 + wn * 64 + fn * 16 + (l & 15);
        if (n < N) {
            const float bias = bihd[n] + bhhd[n];
#pragma unroll
            for (int fm = 0; fm < 4; ++fm) {
                const int mr = m0 + wm * 64 + fm * 16 + (l >> 4) * 4;
#pragma unroll
                for (int r = 0; r < 4; ++r)
                    st1(Xod + (size_t)(mr + r) * N + n, acc[fm][fn][r] + bias);
            }
        }
    }
}

// ---------------------------------------------------------------------------
// H=16 scan, k-split: lane l -> unit u = l&15, k-group g = l>>4 (4 k's each).
// Each lane: 4 FMAs per gate over its k-slice, then shfl_xor(16,32) tree
// reduce; all 64 lanes end with full gate sums for unit u -> redundant cell
// update; no LDS, no barriers. Serial chain ~125 cy/step.
// ---------------------------------------------------------------------------
template<int PF, typename XT, typename AT>
__global__ __launch_bounds__(64, 1) void lstm_scan16(
    const XT* __restrict__ Xf, const XT* __restrict__ Xb_,
    AT* __restrict__ act, const float* __restrict__ whh,
    float* __restrict__ stats, float* __restrict__ state,
    int t0f, int tb_out, int CS, int first)
{
    const int l = threadIdx.x;
    const int dir = (blockIdx.x >= 64) ? 1 : 0;
    const int b = blockIdx.x & 63;
    const int u = l & 15;
    const int g4 = (l >> 4) * 4;   // this lane's k-slice start

    float wi[4], wf_[4], wg[4], wo[4];
#pragma unroll
    for (int i = 0; i < 4; ++i) {
        wi[i]  = whh[(size_t)(dir * 64 +      u) * 16 + g4 + i];
        wf_[i] = whh[(size_t)(dir * 64 + 16 + u) * 16 + g4 + i];
        wg[i]  = whh[(size_t)(dir * 64 + 32 + u) * 16 + g4 + i];
        wo[i]  = whh[(size_t)(dir * 64 + 48 + u) * 16 + g4 + i];
    }

    const int sbase = (dir * 64 + b) * 32;
    float hv = 0.f, cc = 0.f, s1 = 0.f, s2 = 0.f;
    if (!first) { hv = state[sbase + u]; cc = state[sbase + 16 + u]; }

    const XT* Xd = (dir ? Xb_ : Xf) + (size_t)b * 64 + u;
    const size_t rstride = (size_t)64 * 64;
    float xw[PF][4];
#pragma unroll
    for (int p = 0; p < PF; ++p) {
        const size_t ro = (size_t)(dir ? (CS - 1 - p) : p) * rstride;
        xw[p][0] = ld1(Xd + ro);      xw[p][1] = ld1(Xd + ro + 16);
        xw[p][2] = ld1(Xd + ro + 32); xw[p][3] = ld1(Xd + ro + 48);
    }

    for (int tb = 0; tb < CS; tb += PF) {
#pragma unroll
        for (int p = 0; p < PF; ++p) {
            const int pstep = tb + p;
            // gather this lane's h k-slice from lanes g4..g4+3 (which hold h[k])
            const float h0 = shflf(hv, g4 + 0);
            const float h1 = shflf(hv, g4 + 1);
            const float h2 = shflf(hv, g4 + 2);
            const float h3 = shflf(hv, g4 + 3);
            float gi = h0 * wi[0]  + h1 * wi[1]  + h2 * wi[2]  + h3 * wi[3];
            float gf = h0 * wf_[0] + h1 * wf_[1] + h2 * wf_[2] + h3 * wf_[3];
            float gg = h0 * wg[0]  + h1 * wg[1]  + h2 * wg[2]  + h3 * wg[3];
            float go = h0 * wo[0]  + h1 * wo[1]  + h2 * wo[2]  + h3 * wo[3];
            // tree-reduce across the 4 k-groups
            gi += shflxf(gi, 16); gi += shflxf(gi, 32);
            gf += shflxf(gf, 16); gf += shflxf(gf, 32);
            gg += shflxf(gg, 16); gg += shflxf(gg, 32);
            go += shflxf(go, 16); go += shflxf(go, 32);
            gi += xw[p][0]; gf += xw[p][1]; gg += xw[p][2]; go += xw[p][3];
            if (pstep + PF < CS) {
                const size_t ro = (size_t)(dir ? (CS - 1 - (pstep + PF)) : (pstep + PF)) * rstride;
                xw[p][0] = ld1(Xd + ro);      xw[p][1] = ld1(Xd + ro + 16);
                xw[p][2] = ld1(Xd + ro + 32); xw[p][3] = ld1(Xd + ro + 48);
            }
            cc = sigm(gf) * cc + sigm(gi) * tanh_f(gg);
            hv = sigm(go) * tanh_f(cc);
            if (l < 16) {
                AT hq; st1(&hq, hv);
                const float hs = ld1(&hq);
                const int tt = dir ? (tb_out - pstep) : (t0f + pstep);
                act[((size_t)tt * B + b) * 32 + dir * 16 + l] = hq;
                s1 += hs; s2 += hs * hs;
            }
        }
    }
    if (l < 16) {
        state[sbase + l] = hv;
        state[sbase + 16 + l] = cc;
        atomicAdd(stats + dir * 16 + l, s1);
        atomicAdd(stats + 32 + dir * 16 + l, s2);
    }
}

// ---------------------------------------------------------------------------
// H=32 scan: ONE wave per chain. Lane j owns gate rows j (i/f) and 64+j (g/o).
// h broadcast via shfl from lanes 0-31.
// ---------------------------------------------------------------------------
template<int PF, typename XT, typename AT>
__global__ __launch_bounds__(64, 1) void lstm_scan32(
    const XT* __restrict__ Xf, const XT* __restrict__ Xb_,
    AT* __restrict__ act, const float* __restrict__ whh,
    float* __restrict__ stats, float* __restrict__ state,
    int t0f, int tb_out, int CS, int first)
{
    const int j = threadIdx.x;
    const int dir = (blockIdx.x >= 64) ? 1 : 0;
    const int b = blockIdx.x & 63;
    const int u = j & 31;

    float w0[32], w1[32];
#pragma unroll
    for (int k = 0; k < 32; ++k) {
        w0[k] = whh[(size_t)(dir * 128 + j) * 32 + k];
        w1[k] = whh[(size_t)(dir * 128 + 64 + j) * 32 + k];
    }

    const int sbase = (dir * 64 + b) * 64;
    float hv = 0.f, cc = 0.f, s1 = 0.f, s2 = 0.f;
    if (!first) { hv = state[sbase + u]; cc = state[sbase + 32 + u]; }

    const XT* Xd = (dir ? Xb_ : Xf) + (size_t)b * 128 + j;
    const size_t rstride = (size_t)64 * 128;
    float xwA[PF], xwB[PF];
#pragma unroll
    for (int p = 0; p < PF; ++p) {
        const size_t ro = (size_t)(dir ? (CS - 1 - p) : p) * rstride;
        xwA[p] = ld1(Xd + ro); xwB[p] = ld1(Xd + ro + 64);
    }

    for (int tb = 0; tb < CS; tb += PF) {
#pragma unroll
        for (int p = 0; p < PF; ++p) {
            const int pstep = tb + p;
            float gA = xwA[p], gB = xwB[p];
#pragma unroll
            for (int k = 0; k < 32; ++k) {
                const float s = shflf(hv, k);
                gA += s * w0[k]; gB += s * w1[k];
            }
            if (pstep + PF < CS) {
                const size_t ro = (size_t)(dir ? (CS - 1 - (pstep + PF)) : (pstep + PF)) * rstride;
                xwA[p] = ld1(Xd + ro); xwB[p] = ld1(Xd + ro + 64);
            }
            const float iv = shflf(gA, u);
            const float fv = shflf(gA, u + 32);
            const float gv = shflf(gB, u);
            const float ov = shflf(gB, u + 32);
            cc = sigm(fv) * cc + sigm(iv) * tanh_f(gv);
            hv = sigm(ov) * tanh_f(cc);
            if (j < 32) {
                AT hq; st1(&hq, hv);
                const float hs = ld1(&hq);
                const int tt = dir ? (tb_out - pstep) : (t0f + pstep);
                act[((size_t)tt * B + b) * 64 + dir * 32 + j] = hq;
                s1 += hs; s2 += hs * hs;
            }
        }
    }
    if (j < 32) {
        state[sbase + j] = hv;
        state[sbase + 32 + j] = cc;
        atomicAdd(stats + dir * 32 + j, s1);
        atomicAdd(stats + 64 + dir * 32 + j, s2);
    }
}

// ---------------------------------------------------------------------------
// H=64/128 scan: LDS h broadcast, 2 barriers/step, R=1 row/thread (T = 4H
// threads) -- per-thread weights = H VGPRs, no spill.
// ---------------------------------------------------------------------------
template<int H, int R, int PF, typename XT, typename AT>
__global__ __launch_bounds__(4 * H / R, 1) void lstm_scan(
    const XT* __restrict__ Xf, const XT* __restrict__ Xb_,
    AT* __restrict__ act, const float* __restrict__ whh,
    float* __restrict__ stats, float* __restrict__ state,
    int t0f, int tb_out, int CS, int first)
{
    constexpr int N4 = 4 * H;
    constexpr int T  = N4 / R;
    constexpr int CO = 2 * H;
    const int j   = threadIdx.x;
    const int dir = (blockIdx.x >= 64) ? 1 : 0;
    const int b   = blockIdx.x & 63;

    __shared__ __align__(16) float h_lds[H];
    __shared__ float g_lds[N4];

    float w[R][H];
#pragma unroll
    for (int r = 0; r < R; ++r)
#pragma unroll
        for (int k = 0; k < H; ++k)
            w[r][k] = whh[((size_t)dir * N4 + j + r * T) * H + k];

    const int sbase = (dir * 64 + b) * 2 * H;
    float cc = 0.f, s1 = 0.f, s2 = 0.f;
    if (j < H) {
        float h0 = 0.f;
        if (!first) { h0 = state[sbase + j]; cc = state[sbase + H + j]; }
        h_lds[j] = h0;
    }
    __syncthreads();

    const XT* Xd = (dir ? Xb_ : Xf) + (size_t)b * N4 + j;
    const size_t rstride = (size_t)64 * N4;

    float xw[PF][R];
#pragma unroll
    for (int p = 0; p < PF; ++p) {
        const int row = dir ? (CS - 1 - p) : p;
#pragma unroll
        for (int r = 0; r < R; ++r)
            xw[p][r] = ld1(Xd + (size_t)row * rstride + r * T);
    }

    for (int tb = 0; tb < CS; tb += PF) {
#pragma unroll
        for (int p = 0; p < PF; ++p) {
            const int pstep = tb + p;
            float acc0[R], acc1[R], acc2[R], acc3[R];
#pragma unroll
            for (int r = 0; r < R; ++r) { acc0[r] = 0.f; acc1[r] = 0.f; acc2[r] = 0.f; acc3[r] = 0.f; }
            const float4* h4 = (const float4*)h_lds;
#pragma unroll
            for (int k4 = 0; k4 < H / 4; ++k4) {
                const float4 hv = h4[k4];
#pragma unroll
                for (int r = 0; r < R; ++r) {
                    acc0[r] += w[r][4 * k4 + 0] * hv.x;
                    acc1[r] += w[r][4 * k4 + 1] * hv.y;
                    acc2[r] += w[r][4 * k4 + 2] * hv.z;
                    acc3[r] += w[r][4 * k4 + 3] * hv.w;
                }
            }
            float g[R];
#pragma unroll
            for (int r = 0; r < R; ++r)
                g[r] = (acc0[r] + acc1[r]) + (acc2[r] + acc3[r]) + xw[p][r];
            if (pstep + PF < CS) {
                const int row = dir ? (CS - 1 - (pstep + PF)) : (pstep + PF);
#pragma unroll
                for (int r = 0; r < R; ++r)
                    xw[p][r] = ld1(Xd + (size_t)row * rstride + r * T);
            }
#pragma unroll
            for (int r = 0; r < R; ++r) g_lds[j + r * T] = g[r];
            __syncthreads();
            if (j < H) {
                const float fi = sigm(g_lds[j]);
                const float ff = sigm(g_lds[H + j]);
                const float fg = tanh_f(g_lds[2 * H + j]);
                const float fo = sigm(g_lds[3 * H + j]);
                cc = ff * cc + fi * fg;
                const float hv = fo * tanh_f(cc);
                h_lds[j] = hv;
                AT hq; st1(&hq, hv);
                const float hs = ld1(&hq);
                const int tt = dir ? (tb_out - pstep) : (t0f + pstep);
                act[((size_t)tt * B + b) * CO + dir * H + j] = hq;
                s1 += hs; s2 += hs * hs;
            }
            __syncthreads();
        }
    }
    if (j < H) {
        state[sbase + j]     = h_lds[j];
        state[sbase + H + j] = cc;
        atomicAdd(stats + dir * H + j, s1);
        atomicAdd(stats + CO + dir * H + j, s2);
    }
}

// ---------------------------------------------------------------------------
// BN finalize: scg = gamma*rsqrt(var+eps), sb = beta - mean*scg
// ---------------------------------------------------------------------------
__global__ void bn_finalize(const float* __restrict__ sums, float* __restrict__ scg_sb,
                            const float* __restrict__ gamma, const float* __restrict__ beta,
                            int CO)
{
    const int c = threadIdx.x;
    if (c < CO) {
        const float inv  = 1.0f / (float)M;
        const float mean = sums[c] * inv;
        const float var  = fmaxf(sums[CO + c] * inv - mean * mean, 0.f);
        const float s    = gamma[c] * rsqrtf(var + 1e-5f);
        scg_sb[c]      = s;
        scg_sb[CO + c] = beta[c] - mean * s;
    }
}

// ---------------------------------------------------------------------------
// Final FC: out[b,s,j] = sum_c bn3(act[s,b,c]) * fc_w[j,c] + fc_b[j], j<11
// ---------------------------------------------------------------------------
template<typename AT>
__global__ __launch_bounds__(256) void fc_kernel(
    const AT* __restrict__ act, const float* __restrict__ scg_sb,
    const float* __restrict__ fc_w, const float* __restrict__ fc_b,
    float* __restrict__ out)
{
    __shared__ __align__(16) float a_s[32][264];
    __shared__ __align__(16) float w_s[11][264];
    const int tid = threadIdx.x;
    const int m0  = blockIdx.x * 32;
#pragma unroll
    for (int u = 0; u < 12; ++u) {
        int q = u * 256 + tid;
        int uu = q >> 8, c = q & 255;
        if (uu < 11) w_s[uu][c] = fc_w[uu * 256 + c];
    }
#pragma unroll
    for (int u = 0; u < 8; ++u) {
        int q = u * 256 + tid;
        int r = q >> 6, c4 = q & 63;
        const float4 a4 = ld4(act + (size_t)(m0 + r) * 256 + c4 * 4);
        const float4 g4 = *(const float4*)(scg_sb + c4 * 4);
        const float4 b4 = *(const float4*)(scg_sb + 256 + c4 * 4);
        float4 v;
        v.x = a4.x * g4.x + b4.x; v.y = a4.y * g4.y + b4.y;
        v.z = a4.z * g4.z + b4.z; v.w = a4.w * g4.w + b4.w;
        *(float4*)&a_s[r][c4 * 4] = v;
    }
    __syncthreads();
    const int r = tid >> 3, jj = tid & 7;
    const size_t m = (size_t)m0 + r;
    float* orow = out + ((m & 63) * S + (m >> 6)) * 11;
#pragma unroll
    for (int jv = 0; jv < 2; ++jv) {
        const int j = jj + jv * 8;
        if (j < 11) {
            float a0 = 0, a1 = 0, a2 = 0, a3 = 0;
#pragma unroll
            for (int c4 = 0; c4 < 64; ++c4) {
                const float4 av = *(const float4*)&a_s[r][c4 * 4];
                const float4 wv = *(const float4*)&w_s[j][c4 * 4];
                a0 += av.x * wv.x; a1 += av.y * wv.y;
                a2 += av.z * wv.z; a3 += av.w * wv.w;
            }
            orow[j] = (a0 + a1) + (a2 + a3) + fc_b[j];
        }
    }
}

// ---------------------------------------------------------------------------
// One bidirectional layer, time-chunked; ping-pong act buffers; fwd+bwd
// projections fused into ONE gemm launch (gridDim.z = 2).
// ---------------------------------------------------------------------------
template<int H, typename XT, typename AT, typename AIN>
static void run_layer(const AIN* A, const float* wih, const float* whh,
                      const float* bih, const float* bhh,
                      const float* scg_prev, AT* act_out,
                      float* stats_l, float* state, XT* Xbuf,
                      int K, int mode, int CS, hipStream_t stream)
{
    const int N4 = 4 * H, P = S / CS;
    const size_t half = (size_t)CS * 64 * N4;
    XT* Xf = Xbuf;
    XT* Xb = Xbuf + half;
    const dim3 gg(CS * 64 / 128, (N4 + 127) / 128, 2);
    for (int jc = 0; jc < P; ++jc) {
        gemm_mfma<XT, AIN><<<gg, 256, 0, stream>>>(
            A, wih, bih, bhh, scg_prev, Xf, K, N4, mode,
            jc * CS, S - (jc + 1) * CS, half);
        if constexpr (H == 16)
            lstm_scan16<4, XT, AT><<<128, 64, 0, stream>>>(
                Xf, Xb, act_out, whh, stats_l, state, jc * CS, S - 1 - jc * CS, CS, jc == 0);
        else if constexpr (H == 32)
            lstm_scan32<4, XT, AT><<<128, 64, 0, stream>>>(
                Xf, Xb, act_out, whh, stats_l, state, jc * CS, S - 1 - jc * CS, CS, jc == 0);
        else
            lstm_scan<H, 1, 4, XT, AT><<<128, 4 * H, 0, stream>>>(
                Xf, Xb, act_out, whh, stats_l, state, jc * CS, S - 1 - jc * CS, CS, jc == 0);
    }
}

// ---------------------------------------------------------------------------
// Orchestration (inputs order: x, then per layer wih/whh/bih/bhh/gamma/beta,
// then fc_w/fc_b). ws: stats[4096 f32] | state[32768 f32] | actA | actB | X.
// ---------------------------------------------------------------------------
template<typename XT, typename AT>
static void run_all(void* const* d_in, float* out, float* stats, float* state,
                    AT* actA, AT* actB, XT* Xbuf, const int* CS, hipStream_t stream)
{
    auto in = [&](int i) { return (const float*)d_in[i]; };
    zero_stats<<<16, 256, 0, stream>>>(stats);

    run_layer<16, XT, AT, float>((const float*)d_in[0], in(1), in(2), in(3), in(4),
                                 nullptr, actA, stats + 0, state, Xbuf, 7, 0, CS[0], stream);
    bn_finalize<<<1, 256, 0, stream>>>(stats + 0, stats + 512, in(5), in(6), 32);

    run_layer<32, XT, AT, AT>(actA, in(7), in(8), in(9), in(10),
                              stats + 512, actB, stats + 1024, state, Xbuf, 32, 1, CS[1], stream);
    bn_finalize<<<1, 256, 0, stream>>>(stats + 1024, stats + 1536, in(11), in(12), 64);

    run_layer<64, XT, AT, AT>(actB, in(13), in(14), in(15), in(16),
                              stats + 1536, actA, stats + 2048, state, Xbuf, 64, 1, CS[2], stream);
    bn_finalize<<<1, 256, 0, stream>>>(stats + 2048, stats + 2560, in(17), in(18), 128);

    run_layer<128, XT, AT, AT>(actA, in(19), in(20), in(21), in(22),
                               stats + 2560, actB, stats + 3072, state, Xbuf, 128, 1, CS[3], stream);
    bn_finalize<<<1, 256, 0, stream>>>(stats + 3072, stats + 3584, in(23), in(24), 256);

    fc_kernel<AT><<<M / 32, 256, 0, stream>>>(actB, stats + 3584, in(25), in(26), out);
}

// largest power-of-2 chunk CS in [64, 2048] whose 2-window X fits in xavail
static inline int fit_cs(size_t xavail, size_t bytes_per_step) {
    for (int cs = 2048; cs >= 64; cs >>= 1)
        if ((size_t)cs * bytes_per_step <= xavail) return cs;
    return 64;
}

extern "C" void kernel_launch(void* const* d_in, const int* in_sizes, int n_in,
                              void* d_out, int out_size, void* d_ws, size_t ws_size,
                              hipStream_t stream)
{
    (void)in_sizes; (void)n_in; (void)out_size;
    float* out = (float*)d_out;
    char* ws = (char*)d_ws;
    const size_t STB  = 16384;                 // stats: 4096 f32
    const size_t STT  = 131072;                // state: 2*64*2*128 f32
    const size_t HEAD = STB + STT;
    const size_t AAf  = (size_t)M * 128 * 4;   // actA fp32 (64 MiB)
    const size_t ABf  = (size_t)M * 256 * 4;   // actB fp32 (128 MiB)
    const size_t XF3  = (size_t)M * 1024 * 4;  // layer3 full fp32 X (537 MiB)
    const size_t XGOOD = (size_t)140 * 1024 * 1024;  // X room for CS>=~1024 at bf16
    const int H8[4] = {128, 256, 512, 1024};   // both-dir X cols per layer

    float* stats = (float*)ws;
    float* state = (float*)(ws + STB);
    char*  bufs  = ws + HEAD;
    int CS[4];

    if (ws_size >= HEAD + AAf + ABf + XF3) {
        // Plan A: all fp32, full-length X (no chunk loops)
        float* actA = (float*)bufs;
        float* actB = (float*)(bufs + AAf);
        float* X    = (float*)(bufs + AAf + ABf);
        const size_t xavail = ws_size - HEAD - AAf - ABf;
        for (int l = 0; l < 4; ++l) CS[l] = fit_cs(xavail, (size_t)64 * H8[l] * 4);
        run_all<float, float>(d_in, out, stats, state, actA, actB, X, CS, stream);
    } else if (ws_size >= HEAD + AAf + ABf + XGOOD) {
        // Plan B: fp32 act, bf16 X, big chunks
        float* actA = (float*)bufs;
        float* actB = (float*)(bufs + AAf);
        __hip_bfloat16* X = (__hip_bfloat16*)(bufs + AAf + ABf);
        const size_t xavail = ws_size - HEAD - AAf - ABf;
        for (int l = 0; l < 4; ++l) CS[l] = fit_cs(xavail, (size_t)64 * H8[l] * 2);
        run_all<__hip_bfloat16, float>(d_in, out, stats, state, actA, actB, X, CS, stream);
    } else {
        // Plan C: bf16 act + bf16 X -- frees 96 MiB for X so chunks stay big
        // (launch-count kill: ~185 dispatches -> ~22 at ws ~= 200 MiB)
        __hip_bfloat16* actA = (__hip_bfloat16*)bufs;
        __hip_bfloat16* actB = (__hip_bfloat16*)(bufs + AAf / 2);
        __hip_bfloat16* X    = (__hip_bfloat16*)(bufs + AAf / 2 + ABf / 2);
        const size_t used = HEAD + AAf / 2 + ABf / 2;
        const size_t xavail = (ws_size > used) ? (ws_size - used) : 0;
        for (int l = 0; l < 4; ++l) CS[l] = fit_cs(xavail, (size_t)64 * H8[l] * 2);
        run_all<__hip_bfloat16, __hip_bfloat16>(d_in, out, stats, state, actA, actB, X, CS, stream);
    }
}

// Round 11
// 7230.653 us; speedup vs baseline: 1.2822x; 1.2490x over previous
//
#include <hip/hip_runtime.h>
#include <hip/hip_bf16.h>

#define DEVI __device__ __forceinline__

static constexpr int S = 2048;
static constexpr int B = 64;
static constexpr int M = S * B; // 131072

typedef __attribute__((ext_vector_type(8))) short bf16x8;
typedef __attribute__((ext_vector_type(4))) float f32x4;

DEVI float sigm(float x)   { return 1.0f / (1.0f + __expf(-x)); }
DEVI float tanh_f(float x) { return 1.0f - 2.0f / (1.0f + __expf(2.0f * x)); }

DEVI float ld1(const float* p) { return *p; }
DEVI float ld1(const __hip_bfloat16* p) { return __bfloat162float(*p); }
DEVI void  st1(float* p, float v) { *p = v; }
DEVI void  st1(__hip_bfloat16* p, float v) { *p = __float2bfloat16(v); }

DEVI float4 ld4(const float* p) { return *(const float4*)p; }
DEVI float4 ld4(const __hip_bfloat16* p) {
    const ushort4 u = *(const ushort4*)p;   // 8B-aligned: k%4==0, K%4==0
    union { unsigned int i; float f; } a, b, c, d;
    a.i = (unsigned)u.x << 16; b.i = (unsigned)u.y << 16;
    c.i = (unsigned)u.z << 16; d.i = (unsigned)u.w << 16;
    return make_float4(a.f, b.f, c.f, d.f);
}

DEVI unsigned short f2bf(float v) { __hip_bfloat16 h = __float2bfloat16(v); return *(unsigned short*)&h; }

DEVI float shflf(float v, int lane) { return __shfl(v, lane, 64); }
DEVI float shflxf(float v, int mask) { return __shfl_xor(v, mask, 64); }

// ---------------------------------------------------------------------------
// zero the stats scratch (4 layers x 1024 floats)
// ---------------------------------------------------------------------------
__global__ void zero_stats(float* stats) {
    stats[blockIdx.x * 256 + threadIdx.x] = 0.f;
}

// ---------------------------------------------------------------------------
// xW projection GEMM (bf16 MFMA, fp32 accum), BOTH directions (blockIdx.z),
// one time window of CS steps per direction.
//   Xo[z][m][n] = sum_k Anorm(m,k)*W[z](n,k) + bih[z][n] + bhh[z][n]
// Window row m: b = m & 63, s = t0z + (m >> 6), t0z = z ? t0b : t0f.
//   mode==0 -> A = raw x [B,S,7] (K=7, scalar-staged, k-guarded)
//   mode==1 -> A = act [M,K], normalized on the fly: a*scg[k]+sb[k] (K%32==0)
// Tile: BM=128, BN=128, BK=32; 256 thr = 4 waves (2x2), 64x64 per wave.
// ---------------------------------------------------------------------------
template<typename XT, typename AT>
__global__ __launch_bounds__(256) void gemm_mfma(
    const AT* __restrict__ A, const float* __restrict__ W,
    const float* __restrict__ bih, const float* __restrict__ bhh,
    const float* __restrict__ scg_sb, XT* __restrict__ Xo,
    int K, int N, int mode, int t0f, int t0b, size_t halfElems)
{
    __shared__ __align__(16) unsigned short As[128][40];  // [row][k] bf16, pad 32->40
    __shared__ __align__(16) unsigned short Bs[128][40];
    const int tid = threadIdx.x;
    const int m0 = blockIdx.x * 128;
    const int n0 = blockIdx.y * 128;
    const int dz = blockIdx.z;
    const int t0 = dz ? t0b : t0f;
    const float* Wd   = W   + (size_t)dz * N * K;
    const float* bihd = bih + (size_t)dz * N;
    const float* bhhd = bhh + (size_t)dz * N;
    XT* Xod = Xo + (size_t)dz * halfElems;
    const int l  = tid & 63, wid = tid >> 6;
    const int wm = wid >> 1, wn = wid & 1;

    f32x4 acc[4][4];
#pragma unroll
    for (int fm = 0; fm < 4; ++fm)
#pragma unroll
        for (int fn = 0; fn < 4; ++fn) acc[fm][fn] = (f32x4){0.f, 0.f, 0.f, 0.f};

    const int nks = (K + 31) / 32;
    for (int ks = 0; ks < nks; ++ks) {
        const int kc = ks * 32;
        // ---- stage A tile [128][32]
        if (mode == 1) {
#pragma unroll
            for (int it = 0; it < 4; ++it) {
                const int idx = it * 256 + tid;          // 1024 float4 groups
                const int row = idx >> 3, k4 = (idx & 7) * 4;
                const int m = m0 + row;
                const size_t ma = (size_t)(t0 + (m >> 6)) * 64 + (m & 63);
                const float4 a4 = ld4(A + ma * K + kc + k4);
                const float4 g4 = *(const float4*)(scg_sb + kc + k4);
                const float4 b4 = *(const float4*)(scg_sb + K + kc + k4);
                ushort4 u;
                u.x = f2bf(a4.x * g4.x + b4.x); u.y = f2bf(a4.y * g4.y + b4.y);
                u.z = f2bf(a4.z * g4.z + b4.z); u.w = f2bf(a4.w * g4.w + b4.w);
                *(ushort4*)&As[row][k4] = u;
            }
        } else {  // K==7 raw input
#pragma unroll
            for (int it = 0; it < 16; ++it) {
                const int idx = it * 256 + tid;
                const int row = idx >> 5, kk = idx & 31;
                const int m = m0 + row;
                float v = 0.f;
                if (kk < K)
                    v = ld1(A + ((size_t)(m & 63) * S + (t0 + (m >> 6))) * K + kk);
                As[row][kk] = f2bf(v);
            }
        }
        // ---- stage B tile: Bs[n][k] = Wd[n0+n][kc+k], zero outside N/K
        if (!(K & 3)) {
#pragma unroll
            for (int it = 0; it < 4; ++it) {
                const int idx = it * 256 + tid;
                const int row = idx >> 3, k4 = (idx & 7) * 4;
                const int n = n0 + row;
                float4 w4 = make_float4(0.f, 0.f, 0.f, 0.f);
                if (n < N) w4 = *(const float4*)(Wd + (size_t)n * K + kc + k4);
                ushort4 u;
                u.x = f2bf(w4.x); u.y = f2bf(w4.y); u.z = f2bf(w4.z); u.w = f2bf(w4.w);
                *(ushort4*)&Bs[row][k4] = u;
            }
        } else {
#pragma unroll
            for (int it = 0; it < 16; ++it) {
                const int idx = it * 256 + tid;
                const int row = idx >> 5, kk = idx & 31;
                const int n = n0 + row;
                float v = 0.f;
                if (n < N && kk < K) v = Wd[(size_t)n * K + kk];
                Bs[row][kk] = f2bf(v);
            }
        }
        __syncthreads();
        // ---- fragments + MFMA
        bf16x8 af[4], bw[4];
#pragma unroll
        for (int f = 0; f < 4; ++f) {
            af[f] = *(const bf16x8*)&As[wm * 64 + f * 16 + (l & 15)][(l >> 4) * 8];
            bw[f] = *(const bf16x8*)&Bs[wn * 64 + f * 16 + (l & 15)][(l >> 4) * 8];
        }
#pragma unroll
        for (int fm = 0; fm < 4; ++fm)
#pragma unroll
            for (int fn = 0; fn < 4; ++fn)
                acc[fm][fn] = __builtin_amdgcn_mfma_f32_16x16x32_bf16(af[fm], bw[fn], acc[fm][fn], 0, 0, 0);
        __syncthreads();
    }
    // ---- epilogue: D col = lane&15, row = (lane>>4)*4 + r  [m89/m91 layout]
#pragma unroll
    for (int fn = 0; fn < 4; ++fn) {
        const int n = n0 + wn * 64 + fn * 16 + (l & 15);
        if (n < N) {
            const float bias = bihd[n] + bhhd[n];
#pragma unroll
            for (int fm = 0; fm < 4; ++fm) {
                const int mr = m0 + wm * 64 + fm * 16 + (l >> 4) * 4;
#pragma unroll
                for (int r = 0; r < 4; ++r)
                    st1(Xod + (size_t)(mr + r) * N + n, acc[fm][fn][r] + bias);
            }
        }
    }
}

// ---------------------------------------------------------------------------
// H=16 scan, k-split: lane l -> unit u = l&15, k-group g = l>>4 (4 k's each).
// 4 FMAs per gate per lane + shfl_xor(16,32) tree reduce; no LDS/barriers.
// ---------------------------------------------------------------------------
template<int PF, typename XT, typename AT>
__global__ __launch_bounds__(64, 1) void lstm_scan16(
    const XT* __restrict__ Xf, const XT* __restrict__ Xb_,
    AT* __restrict__ act, const float* __restrict__ whh,
    float* __restrict__ stats, float* __restrict__ state,
    int t0f, int tb_out, int CS, int first)
{
    const int l = threadIdx.x;
    const int dir = (blockIdx.x >= 64) ? 1 : 0;
    const int b = blockIdx.x & 63;
    const int u = l & 15;
    const int g4 = (l >> 4) * 4;   // this lane's k-slice start

    float wi[4], wf_[4], wg[4], wo[4];
#pragma unroll
    for (int i = 0; i < 4; ++i) {
        wi[i]  = whh[(size_t)(dir * 64 +      u) * 16 + g4 + i];
        wf_[i] = whh[(size_t)(dir * 64 + 16 + u) * 16 + g4 + i];
        wg[i]  = whh[(size_t)(dir * 64 + 32 + u) * 16 + g4 + i];
        wo[i]  = whh[(size_t)(dir * 64 + 48 + u) * 16 + g4 + i];
    }

    const int sbase = (dir * 64 + b) * 32;
    float hv = 0.f, cc = 0.f, s1 = 0.f, s2 = 0.f;
    if (!first) { hv = state[sbase + u]; cc = state[sbase + 16 + u]; }

    const XT* Xd = (dir ? Xb_ : Xf) + (size_t)b * 64 + u;
    const size_t rstride = (size_t)64 * 64;
    float xw[PF][4];
#pragma unroll
    for (int p = 0; p < PF; ++p) {
        const size_t ro = (size_t)(dir ? (CS - 1 - p) : p) * rstride;
        xw[p][0] = ld1(Xd + ro);      xw[p][1] = ld1(Xd + ro + 16);
        xw[p][2] = ld1(Xd + ro + 32); xw[p][3] = ld1(Xd + ro + 48);
    }

    for (int tb = 0; tb < CS; tb += PF) {
#pragma unroll
        for (int p = 0; p < PF; ++p) {
            const int pstep = tb + p;
            const float h0 = shflf(hv, g4 + 0);
            const float h1 = shflf(hv, g4 + 1);
            const float h2 = shflf(hv, g4 + 2);
            const float h3 = shflf(hv, g4 + 3);
            float gi = h0 * wi[0]  + h1 * wi[1]  + h2 * wi[2]  + h3 * wi[3];
            float gf = h0 * wf_[0] + h1 * wf_[1] + h2 * wf_[2] + h3 * wf_[3];
            float gg = h0 * wg[0]  + h1 * wg[1]  + h2 * wg[2]  + h3 * wg[3];
            float go = h0 * wo[0]  + h1 * wo[1]  + h2 * wo[2]  + h3 * wo[3];
            gi += shflxf(gi, 16); gi += shflxf(gi, 32);
            gf += shflxf(gf, 16); gf += shflxf(gf, 32);
            gg += shflxf(gg, 16); gg += shflxf(gg, 32);
            go += shflxf(go, 16); go += shflxf(go, 32);
            gi += xw[p][0]; gf += xw[p][1]; gg += xw[p][2]; go += xw[p][3];
            if (pstep + PF < CS) {
                const size_t ro = (size_t)(dir ? (CS - 1 - (pstep + PF)) : (pstep + PF)) * rstride;
                xw[p][0] = ld1(Xd + ro);      xw[p][1] = ld1(Xd + ro + 16);
                xw[p][2] = ld1(Xd + ro + 32); xw[p][3] = ld1(Xd + ro + 48);
            }
            cc = sigm(gf) * cc + sigm(gi) * tanh_f(gg);
            hv = sigm(go) * tanh_f(cc);
            if (l < 16) {
                AT hq; st1(&hq, hv);
                const float hs = ld1(&hq);
                const int tt = dir ? (tb_out - pstep) : (t0f + pstep);
                act[((size_t)tt * B + b) * 32 + dir * 16 + l] = hq;
                s1 += hs; s2 += hs * hs;
            }
        }
    }
    if (l < 16) {
        state[sbase + l] = hv;
        state[sbase + 16 + l] = cc;
        atomicAdd(stats + dir * 16 + l, s1);
        atomicAdd(stats + 32 + dir * 16 + l, s2);
    }
}

// ---------------------------------------------------------------------------
// H=32 scan: ONE wave per chain. Lane j owns gate rows j (i/f) and 64+j (g/o).
// h broadcast via shfl from lanes 0-31.
// ---------------------------------------------------------------------------
template<int PF, typename XT, typename AT>
__global__ __launch_bounds__(64, 1) void lstm_scan32(
    const XT* __restrict__ Xf, const XT* __restrict__ Xb_,
    AT* __restrict__ act, const float* __restrict__ whh,
    float* __restrict__ stats, float* __restrict__ state,
    int t0f, int tb_out, int CS, int first)
{
    const int j = threadIdx.x;
    const int dir = (blockIdx.x >= 64) ? 1 : 0;
    const int b = blockIdx.x & 63;
    const int u = j & 31;

    float w0[32], w1[32];
#pragma unroll
    for (int k = 0; k < 32; ++k) {
        w0[k] = whh[(size_t)(dir * 128 + j) * 32 + k];
        w1[k] = whh[(size_t)(dir * 128 + 64 + j) * 32 + k];
    }

    const int sbase = (dir * 64 + b) * 64;
    float hv = 0.f, cc = 0.f, s1 = 0.f, s2 = 0.f;
    if (!first) { hv = state[sbase + u]; cc = state[sbase + 32 + u]; }

    const XT* Xd = (dir ? Xb_ : Xf) + (size_t)b * 128 + j;
    const size_t rstride = (size_t)64 * 128;
    float xwA[PF], xwB[PF];
#pragma unroll
    for (int p = 0; p < PF; ++p) {
        const size_t ro = (size_t)(dir ? (CS - 1 - p) : p) * rstride;
        xwA[p] = ld1(Xd + ro); xwB[p] = ld1(Xd + ro + 64);
    }

    for (int tb = 0; tb < CS; tb += PF) {
#pragma unroll
        for (int p = 0; p < PF; ++p) {
            const int pstep = tb + p;
            float gA = xwA[p], gB = xwB[p];
#pragma unroll
            for (int k = 0; k < 32; ++k) {
                const float s = shflf(hv, k);
                gA += s * w0[k]; gB += s * w1[k];
            }
            if (pstep + PF < CS) {
                const size_t ro = (size_t)(dir ? (CS - 1 - (pstep + PF)) : (pstep + PF)) * rstride;
                xwA[p] = ld1(Xd + ro); xwB[p] = ld1(Xd + ro + 64);
            }
            const float iv = shflf(gA, u);
            const float fv = shflf(gA, u + 32);
            const float gv = shflf(gB, u);
            const float ov = shflf(gB, u + 32);
            cc = sigm(fv) * cc + sigm(iv) * tanh_f(gv);
            hv = sigm(ov) * tanh_f(cc);
            if (j < 32) {
                AT hq; st1(&hq, hv);
                const float hs = ld1(&hq);
                const int tt = dir ? (tb_out - pstep) : (t0f + pstep);
                act[((size_t)tt * B + b) * 64 + dir * 32 + j] = hq;
                s1 += hs; s2 += hs * hs;
            }
        }
    }
    if (j < 32) {
        state[sbase + j] = hv;
        state[sbase + 32 + j] = cc;
        atomicAdd(stats + dir * 32 + j, s1);
        atomicAdd(stats + 64 + dir * 32 + j, s2);
    }
}

// ---------------------------------------------------------------------------
// H=64 scan: LDS h broadcast, 2 barriers/step, R=1 (T=256), w=64/thread --
// fits VGPR budget comfortably.
// ---------------------------------------------------------------------------
template<int H, int R, int PF, typename XT, typename AT>
__global__ __launch_bounds__(4 * H / R, 1) void lstm_scan(
    const XT* __restrict__ Xf, const XT* __restrict__ Xb_,
    AT* __restrict__ act, const float* __restrict__ whh,
    float* __restrict__ stats, float* __restrict__ state,
    int t0f, int tb_out, int CS, int first)
{
    constexpr int N4 = 4 * H;
    constexpr int T  = N4 / R;
    constexpr int CO = 2 * H;
    const int j   = threadIdx.x;
    const int dir = (blockIdx.x >= 64) ? 1 : 0;
    const int b   = blockIdx.x & 63;

    __shared__ __align__(16) float h_lds[H];
    __shared__ float g_lds[N4];

    float w[R][H];
#pragma unroll
    for (int r = 0; r < R; ++r)
#pragma unroll
        for (int k = 0; k < H; ++k)
            w[r][k] = whh[((size_t)dir * N4 + j + r * T) * H + k];

    const int sbase = (dir * 64 + b) * 2 * H;
    float cc = 0.f, s1 = 0.f, s2 = 0.f;
    if (j < H) {
        float h0 = 0.f;
        if (!first) { h0 = state[sbase + j]; cc = state[sbase + H + j]; }
        h_lds[j] = h0;
    }
    __syncthreads();

    const XT* Xd = (dir ? Xb_ : Xf) + (size_t)b * N4 + j;
    const size_t rstride = (size_t)64 * N4;

    float xw[PF][R];
#pragma unroll
    for (int p = 0; p < PF; ++p) {
        const int row = dir ? (CS - 1 - p) : p;
#pragma unroll
        for (int r = 0; r < R; ++r)
            xw[p][r] = ld1(Xd + (size_t)row * rstride + r * T);
    }

    for (int tb = 0; tb < CS; tb += PF) {
#pragma unroll
        for (int p = 0; p < PF; ++p) {
            const int pstep = tb + p;
            float acc0[R], acc1[R], acc2[R], acc3[R];
#pragma unroll
            for (int r = 0; r < R; ++r) { acc0[r] = 0.f; acc1[r] = 0.f; acc2[r] = 0.f; acc3[r] = 0.f; }
            const float4* h4 = (const float4*)h_lds;
#pragma unroll
            for (int k4 = 0; k4 < H / 4; ++k4) {
                const float4 hv = h4[k4];
#pragma unroll
                for (int r = 0; r < R; ++r) {
                    acc0[r] += w[r][4 * k4 + 0] * hv.x;
                    acc1[r] += w[r][4 * k4 + 1] * hv.y;
                    acc2[r] += w[r][4 * k4 + 2] * hv.z;
                    acc3[r] += w[r][4 * k4 + 3] * hv.w;
                }
            }
            float g[R];
#pragma unroll
            for (int r = 0; r < R; ++r)
                g[r] = (acc0[r] + acc1[r]) + (acc2[r] + acc3[r]) + xw[p][r];
            if (pstep + PF < CS) {
                const int row = dir ? (CS - 1 - (pstep + PF)) : (pstep + PF);
#pragma unroll
                for (int r = 0; r < R; ++r)
                    xw[p][r] = ld1(Xd + (size_t)row * rstride + r * T);
            }
#pragma unroll
            for (int r = 0; r < R; ++r) g_lds[j + r * T] = g[r];
            __syncthreads();
            if (j < H) {
                const float fi = sigm(g_lds[j]);
                const float ff = sigm(g_lds[H + j]);
                const float fg = tanh_f(g_lds[2 * H + j]);
                const float fo = sigm(g_lds[3 * H + j]);
                cc = ff * cc + fi * fg;
                const float hv = fo * tanh_f(cc);
                h_lds[j] = hv;
                AT hq; st1(&hq, hv);
                const float hs = ld1(&hq);
                const int tt = dir ? (tb_out - pstep) : (t0f + pstep);
                act[((size_t)tt * B + b) * CO + dir * H + j] = hq;
                s1 += hs; s2 += hs * hs;
            }
            __syncthreads();
        }
    }
    if (j < H) {
        state[sbase + j]     = h_lds[j];
        state[sbase + H + j] = cc;
        atomicAdd(stats + dir * H + j, s1);
        atomicAdd(stats + CO + dir * H + j, s2);
    }
}

// ---------------------------------------------------------------------------
// H=128 scan, K-SPLIT (fixes the round-10 VGPR spill: w[128]+overhead > 128
// allocated => per-step scratch reloads, 2110us/chunk). 1024 threads: thread
// = (gate row j = tid&511, k-half kh = tid>>9); each holds only w[64]
// (~90 VGPR total, fits 4-waves/SIMD 128-VGPR budget). Per step: half-dot ->
// psum[2][512] in LDS -> barrier -> threads<128 combine halves + cell update
// -> barrier. Same math, same 2-barrier structure.
// ---------------------------------------------------------------------------
template<int PF, typename XT, typename AT>
__global__ __launch_bounds__(1024, 1) void lstm_scan128(
    const XT* __restrict__ Xf, const XT* __restrict__ Xb_,
    AT* __restrict__ act, const float* __restrict__ whh,
    float* __restrict__ stats, float* __restrict__ state,
    int t0f, int tb_out, int CS, int first)
{
    const int tid = threadIdx.x;
    const int j   = tid & 511;        // gate row (dir-local)
    const int kh  = tid >> 9;         // k-half: 0 -> k<64, 1 -> k>=64
    const int dir = (blockIdx.x >= 64) ? 1 : 0;
    const int b   = blockIdx.x & 63;

    __shared__ __align__(16) float h_lds[128];
    __shared__ __align__(16) float psum[2][512];

    float w[64];
#pragma unroll
    for (int k = 0; k < 64; ++k)
        w[k] = whh[((size_t)dir * 512 + j) * 128 + kh * 64 + k];

    const int sbase = (dir * 64 + b) * 256;
    float cc = 0.f, s1 = 0.f, s2 = 0.f;
    if (tid < 128) {
        float h0 = 0.f;
        if (!first) { h0 = state[sbase + tid]; cc = state[sbase + 128 + tid]; }
        h_lds[tid] = h0;
    }
    __syncthreads();

    const XT* Xd = (dir ? Xb_ : Xf) + (size_t)b * 512 + j;
    const size_t rstride = (size_t)64 * 512;

    float xw[PF];
    if (kh == 0) {
#pragma unroll
        for (int p = 0; p < PF; ++p) {
            const int row = dir ? (CS - 1 - p) : p;
            xw[p] = ld1(Xd + (size_t)row * rstride);
        }
    }

    for (int tb = 0; tb < CS; tb += PF) {
#pragma unroll
        for (int p = 0; p < PF; ++p) {
            const int pstep = tb + p;
            float a0 = 0.f, a1 = 0.f, a2 = 0.f, a3 = 0.f;
            const float4* h4 = (const float4*)&h_lds[kh * 64];
#pragma unroll
            for (int k4 = 0; k4 < 16; ++k4) {
                const float4 hv = h4[k4];
                a0 += w[4 * k4 + 0] * hv.x;
                a1 += w[4 * k4 + 1] * hv.y;
                a2 += w[4 * k4 + 2] * hv.z;
                a3 += w[4 * k4 + 3] * hv.w;
            }
            float partial = (a0 + a1) + (a2 + a3);
            if (kh == 0) {
                partial += xw[p];
                if (pstep + PF < CS) {
                    const int row = dir ? (CS - 1 - (pstep + PF)) : (pstep + PF);
                    xw[p] = ld1(Xd + (size_t)row * rstride);
                }
            }
            psum[kh][j] = partial;
            __syncthreads();   // psum complete; h reads done
            if (tid < 128) {
                const int u = tid;
                const float gi = psum[0][u]       + psum[1][u];
                const float gf = psum[0][128 + u] + psum[1][128 + u];
                const float gg = psum[0][256 + u] + psum[1][256 + u];
                const float go = psum[0][384 + u] + psum[1][384 + u];
                cc = sigm(gf) * cc + sigm(gi) * tanh_f(gg);
                const float hvv = sigm(go) * tanh_f(cc);
                h_lds[u] = hvv;
                AT hq; st1(&hq, hvv);
                const float hs = ld1(&hq);
                const int tt = dir ? (tb_out - pstep) : (t0f + pstep);
                act[((size_t)tt * B + b) * 256 + dir * 128 + u] = hq;
                s1 += hs; s2 += hs * hs;
            }
            __syncthreads();   // new h visible; psum reusable
        }
    }
    if (tid < 128) {
        state[sbase + tid]       = h_lds[tid];
        state[sbase + 128 + tid] = cc;
        atomicAdd(stats + dir * 128 + tid, s1);
        atomicAdd(stats + 256 + dir * 128 + tid, s2);
    }
}

// ---------------------------------------------------------------------------
// BN finalize: scg = gamma*rsqrt(var+eps), sb = beta - mean*scg
// ---------------------------------------------------------------------------
__global__ void bn_finalize(const float* __restrict__ sums, float* __restrict__ scg_sb,
                            const float* __restrict__ gamma, const float* __restrict__ beta,
                            int CO)
{
    const int c = threadIdx.x;
    if (c < CO) {
        const float inv  = 1.0f / (float)M;
        const float mean = sums[c] * inv;
        const float var  = fmaxf(sums[CO + c] * inv - mean * mean, 0.f);
        const float s    = gamma[c] * rsqrtf(var + 1e-5f);
        scg_sb[c]      = s;
        scg_sb[CO + c] = beta[c] - mean * s;
    }
}

// ---------------------------------------------------------------------------
// Final FC: out[b,s,j] = sum_c bn3(act[s,b,c]) * fc_w[j,c] + fc_b[j], j<11
// ---------------------------------------------------------------------------
template<typename AT>
__global__ __launch_bounds__(256) void fc_kernel(
    const AT* __restrict__ act, const float* __restrict__ scg_sb,
    const float* __restrict__ fc_w, const float* __restrict__ fc_b,
    float* __restrict__ out)
{
    __shared__ __align__(16) float a_s[32][264];
    __shared__ __align__(16) float w_s[11][264];
    const int tid = threadIdx.x;
    const int m0  = blockIdx.x * 32;
#pragma unroll
    for (int u = 0; u < 12; ++u) {
        int q = u * 256 + tid;
        int uu = q >> 8, c = q & 255;
        if (uu < 11) w_s[uu][c] = fc_w[uu * 256 + c];
    }
#pragma unroll
    for (int u = 0; u < 8; ++u) {
        int q = u * 256 + tid;
        int r = q >> 6, c4 = q & 63;
        const float4 a4 = ld4(act + (size_t)(m0 + r) * 256 + c4 * 4);
        const float4 g4 = *(const float4*)(scg_sb + c4 * 4);
        const float4 b4 = *(const float4*)(scg_sb + 256 + c4 * 4);
        float4 v;
        v.x = a4.x * g4.x + b4.x; v.y = a4.y * g4.y + b4.y;
        v.z = a4.z * g4.z + b4.z; v.w = a4.w * g4.w + b4.w;
        *(float4*)&a_s[r][c4 * 4] = v;
    }
    __syncthreads();
    const int r = tid >> 3, jj = tid & 7;
    const size_t m = (size_t)m0 + r;
    float* orow = out + ((m & 63) * S + (m >> 6)) * 11;
#pragma unroll
    for (int jv = 0; jv < 2; ++jv) {
        const int j = jj + jv * 8;
        if (j < 11) {
            float a0 = 0, a1 = 0, a2 = 0, a3 = 0;
#pragma unroll
            for (int c4 = 0; c4 < 64; ++c4) {
                const float4 av = *(const float4*)&a_s[r][c4 * 4];
                const float4 wv = *(const float4*)&w_s[j][c4 * 4];
                a0 += av.x * wv.x; a1 += av.y * wv.y;
                a2 += av.z * wv.z; a3 += av.w * wv.w;
            }
            orow[j] = (a0 + a1) + (a2 + a3) + fc_b[j];
        }
    }
}

// ---------------------------------------------------------------------------
// One bidirectional layer, time-chunked; ping-pong act buffers; fwd+bwd
// projections fused into ONE gemm launch (gridDim.z = 2).
// ---------------------------------------------------------------------------
template<int H, typename XT, typename AT, typename AIN>
static void run_layer(const AIN* A, const float* wih, const float* whh,
                      const float* bih, const float* bhh,
                      const float* scg_prev, AT* act_out,
                      float* stats_l, float* state, XT* Xbuf,
                      int K, int mode, int CS, hipStream_t stream)
{
    const int N4 = 4 * H, P = S / CS;
    const size_t half = (size_t)CS * 64 * N4;
    XT* Xf = Xbuf;
    XT* Xb = Xbuf + half;
    const dim3 gg(CS * 64 / 128, (N4 + 127) / 128, 2);
    for (int jc = 0; jc < P; ++jc) {
        gemm_mfma<XT, AIN><<<gg, 256, 0, stream>>>(
            A, wih, bih, bhh, scg_prev, Xf, K, N4, mode,
            jc * CS, S - (jc + 1) * CS, half);
        if constexpr (H == 16)
            lstm_scan16<4, XT, AT><<<128, 64, 0, stream>>>(
                Xf, Xb, act_out, whh, stats_l, state, jc * CS, S - 1 - jc * CS, CS, jc == 0);
        else if constexpr (H == 32)
            lstm_scan32<4, XT, AT><<<128, 64, 0, stream>>>(
                Xf, Xb, act_out, whh, stats_l, state, jc * CS, S - 1 - jc * CS, CS, jc == 0);
        else if constexpr (H == 128)
            lstm_scan128<4, XT, AT><<<128, 1024, 0, stream>>>(
                Xf, Xb, act_out, whh, stats_l, state, jc * CS, S - 1 - jc * CS, CS, jc == 0);
        else
            lstm_scan<H, 1, 4, XT, AT><<<128, 4 * H, 0, stream>>>(
                Xf, Xb, act_out, whh, stats_l, state, jc * CS, S - 1 - jc * CS, CS, jc == 0);
    }
}

// ---------------------------------------------------------------------------
// Orchestration (inputs order: x, then per layer wih/whh/bih/bhh/gamma/beta,
// then fc_w/fc_b). ws: stats[4096 f32] | state[32768 f32] | actA | actB | X.
// ---------------------------------------------------------------------------
template<typename XT, typename AT>
static void run_all(void* const* d_in, float* out, float* stats, float* state,
                    AT* actA, AT* actB, XT* Xbuf, const int* CS, hipStream_t stream)
{
    auto in = [&](int i) { return (const float*)d_in[i]; };
    zero_stats<<<16, 256, 0, stream>>>(stats);

    run_layer<16, XT, AT, float>((const float*)d_in[0], in(1), in(2), in(3), in(4),
                                 nullptr, actA, stats + 0, state, Xbuf, 7, 0, CS[0], stream);
    bn_finalize<<<1, 256, 0, stream>>>(stats + 0, stats + 512, in(5), in(6), 32);

    run_layer<32, XT, AT, AT>(actA, in(7), in(8), in(9), in(10),
                              stats + 512, actB, stats + 1024, state, Xbuf, 32, 1, CS[1], stream);
    bn_finalize<<<1, 256, 0, stream>>>(stats + 1024, stats + 1536, in(11), in(12), 64);

    run_layer<64, XT, AT, AT>(actB, in(13), in(14), in(15), in(16),
                              stats + 1536, actA, stats + 2048, state, Xbuf, 64, 1, CS[2], stream);
    bn_finalize<<<1, 256, 0, stream>>>(stats + 2048, stats + 2560, in(17), in(18), 128);

    run_layer<128, XT, AT, AT>(actA, in(19), in(20), in(21), in(22),
                               stats + 2560, actB, stats + 3072, state, Xbuf, 128, 1, CS[3], stream);
    bn_finalize<<<1, 256, 0, stream>>>(stats + 3072, stats + 3584, in(23), in(24), 256);

    fc_kernel<AT><<<M / 32, 256, 0, stream>>>(actB, stats + 3584, in(25), in(26), out);
}

// largest power-of-2 chunk CS in [64, 2048] whose 2-window X fits in xavail
static inline int fit_cs(size_t xavail, size_t bytes_per_step) {
    for (int cs = 2048; cs >= 64; cs >>= 1)
        if ((size_t)cs * bytes_per_step <= xavail) return cs;
    return 64;
}

extern "C" void kernel_launch(void* const* d_in, const int* in_sizes, int n_in,
                              void* d_out, int out_size, void* d_ws, size_t ws_size,
                              hipStream_t stream)
{
    (void)in_sizes; (void)n_in; (void)out_size;
    float* out = (float*)d_out;
    char* ws = (char*)d_ws;
    const size_t STB  = 16384;                 // stats: 4096 f32
    const size_t STT  = 131072;                // state: 2*64*2*128 f32
    const size_t HEAD = STB + STT;
    const size_t AAf  = (size_t)M * 128 * 4;   // actA fp32 (64 MiB)
    const size_t ABf  = (size_t)M * 256 * 4;   // actB fp32 (128 MiB)
    const size_t XF3  = (size_t)M * 1024 * 4;  // layer3 full fp32 X (537 MiB)
    const size_t XGOOD = (size_t)140 * 1024 * 1024;  // X room for CS>=~1024 at bf16
    const int H8[4] = {128, 256, 512, 1024};   // both-dir X cols per layer

    float* stats = (float*)ws;
    float* state = (float*)(ws + STB);
    char*  bufs  = ws + HEAD;
    int CS[4];

    if (ws_size >= HEAD + AAf + ABf + XF3) {
        // Plan A: all fp32, full-length X (no chunk loops)
        float* actA = (float*)bufs;
        float* actB = (float*)(bufs + AAf);
        float* X    = (float*)(bufs + AAf + ABf);
        const size_t xavail = ws_size - HEAD - AAf - ABf;
        for (int l = 0; l < 4; ++l) CS[l] = fit_cs(xavail, (size_t)64 * H8[l] * 4);
        run_all<float, float>(d_in, out, stats, state, actA, actB, X, CS, stream);
    } else if (ws_size >= HEAD + AAf + ABf + XGOOD) {
        // Plan B: fp32 act, bf16 X, big chunks
        float* actA = (float*)bufs;
        float* actB = (float*)(bufs + AAf);
        __hip_bfloat16* X = (__hip_bfloat16*)(bufs + AAf + ABf);
        const size_t xavail = ws_size - HEAD - AAf - ABf;
        for (int l = 0; l < 4; ++l) CS[l] = fit_cs(xavail, (size_t)64 * H8[l] * 2);
        run_all<__hip_bfloat16, float>(d_in, out, stats, state, actA, actB, X, CS, stream);
    } else {
        // Plan C: bf16 act + bf16 X -- frees 96 MiB for X so chunks stay big
        __hip_bfloat16* actA = (__hip_bfloat16*)bufs;
        __hip_bfloat16* actB = (__hip_bfloat16*)(bufs + AAf / 2);
        __hip_bfloat16* X    = (__hip_bfloat16*)(bufs + AAf / 2 + ABf / 2);
        const size_t used = HEAD + AAf / 2 + ABf / 2;
        const size_t xavail = (ws_size > used) ? (ws_size - used) : 0;
        for (int l = 0; l < 4; ++l) CS[l] = fit_cs(xavail, (size_t)64 * H8[l] * 2);
        run_all<__hip_bfloat16, __hip_bfloat16>(d_in, out, stats, state, actA, actB, X, CS, stream);
    }
}

// Round 12
// 6937.835 us; speedup vs baseline: 1.3363x; 1.0422x over previous
//
#include <hip/hip_runtime.h>
#include <hip/hip_bf16.h>

#define DEVI __device__ __forceinline__

static constexpr int S = 2048;
static constexpr int B = 64;
static constexpr int M = S * B; // 131072

typedef __attribute__((ext_vector_type(8))) short bf16x8;
typedef __attribute__((ext_vector_type(4))) float f32x4;

DEVI float sigm(float x)   { return 1.0f / (1.0f + __expf(-x)); }
DEVI float tanh_f(float x) { return 1.0f - 2.0f / (1.0f + __expf(2.0f * x)); }

DEVI float ld1(const float* p) { return *p; }
DEVI float ld1(const __hip_bfloat16* p) { return __bfloat162float(*p); }
DEVI void  st1(float* p, float v) { *p = v; }
DEVI void  st1(__hip_bfloat16* p, float v) { *p = __float2bfloat16(v); }

DEVI float4 ld4(const float* p) { return *(const float4*)p; }
DEVI float4 ld4(const __hip_bfloat16* p) {
    const ushort4 u = *(const ushort4*)p;   // 8B-aligned: k%4==0, K%4==0
    union { unsigned int i; float f; } a, b, c, d;
    a.i = (unsigned)u.x << 16; b.i = (unsigned)u.y << 16;
    c.i = (unsigned)u.z << 16; d.i = (unsigned)u.w << 16;
    return make_float4(a.f, b.f, c.f, d.f);
}

DEVI unsigned short f2bf(float v) { __hip_bfloat16 h = __float2bfloat16(v); return *(unsigned short*)&h; }

DEVI float bcastf(float v, int lane) {     // uniform broadcast (v_readlane, SGPR result)
    return __int_as_float(__builtin_amdgcn_readlane(__float_as_int(v), lane));
}
DEVI float shflf(float v, int lane) { return __shfl(v, lane, 64); }
DEVI float shflxf(float v, int mask) { return __shfl_xor(v, mask, 64); }

// ---------------------------------------------------------------------------
// zero the stats scratch (4 layers x 1024 floats)
// ---------------------------------------------------------------------------
__global__ void zero_stats(float* stats) {
    stats[blockIdx.x * 256 + threadIdx.x] = 0.f;
}

// ---------------------------------------------------------------------------
// xW projection GEMM (bf16 MFMA, fp32 accum), BOTH directions (blockIdx.z),
// one time window of CS steps per direction.
//   Xo[z][m][n] = sum_k Anorm(m,k)*W[z](n,k) + bih[z][n] + bhh[z][n]
// Window row m: b = m & 63, s = t0z + (m >> 6).
//   mode==0 -> A = raw x [B,S,7] (K=7)   mode==1 -> A = act [M,K], normalized
// Tile: BM=128, BN=128, BK=32; 256 thr = 4 waves (2x2), 64x64 per wave.
// ---------------------------------------------------------------------------
template<typename XT, typename AT>
__global__ __launch_bounds__(256) void gemm_mfma(
    const AT* __restrict__ A, const float* __restrict__ W,
    const float* __restrict__ bih, const float* __restrict__ bhh,
    const float* __restrict__ scg_sb, XT* __restrict__ Xo,
    int K, int N, int mode, int t0f, int t0b, size_t halfElems)
{
    __shared__ __align__(16) unsigned short As[128][40];  // [row][k] bf16, pad 32->40
    __shared__ __align__(16) unsigned short Bs[128][40];
    const int tid = threadIdx.x;
    const int m0 = blockIdx.x * 128;
    const int n0 = blockIdx.y * 128;
    const int dz = blockIdx.z;
    const int t0 = dz ? t0b : t0f;
    const float* Wd   = W   + (size_t)dz * N * K;
    const float* bihd = bih + (size_t)dz * N;
    const float* bhhd = bhh + (size_t)dz * N;
    XT* Xod = Xo + (size_t)dz * halfElems;
    const int l  = tid & 63, wid = tid >> 6;
    const int wm = wid >> 1, wn = wid & 1;

    f32x4 acc[4][4];
#pragma unroll
    for (int fm = 0; fm < 4; ++fm)
#pragma unroll
        for (int fn = 0; fn < 4; ++fn) acc[fm][fn] = (f32x4){0.f, 0.f, 0.f, 0.f};

    const int nks = (K + 31) / 32;
    for (int ks = 0; ks < nks; ++ks) {
        const int kc = ks * 32;
        if (mode == 1) {
#pragma unroll
            for (int it = 0; it < 4; ++it) {
                const int idx = it * 256 + tid;
                const int row = idx >> 3, k4 = (idx & 7) * 4;
                const int m = m0 + row;
                const size_t ma = (size_t)(t0 + (m >> 6)) * 64 + (m & 63);
                const float4 a4 = ld4(A + ma * K + kc + k4);
                const float4 g4 = *(const float4*)(scg_sb + kc + k4);
                const float4 b4 = *(const float4*)(scg_sb + K + kc + k4);
                ushort4 u;
                u.x = f2bf(a4.x * g4.x + b4.x); u.y = f2bf(a4.y * g4.y + b4.y);
                u.z = f2bf(a4.z * g4.z + b4.z); u.w = f2bf(a4.w * g4.w + b4.w);
                *(ushort4*)&As[row][k4] = u;
            }
        } else {  // K==7 raw input
#pragma unroll
            for (int it = 0; it < 16; ++it) {
                const int idx = it * 256 + tid;
                const int row = idx >> 5, kk = idx & 31;
                const int m = m0 + row;
                float v = 0.f;
                if (kk < K)
                    v = ld1(A + ((size_t)(m & 63) * S + (t0 + (m >> 6))) * K + kk);
                As[row][kk] = f2bf(v);
            }
        }
        if (!(K & 3)) {
#pragma unroll
            for (int it = 0; it < 4; ++it) {
                const int idx = it * 256 + tid;
                const int row = idx >> 3, k4 = (idx & 7) * 4;
                const int n = n0 + row;
                float4 w4 = make_float4(0.f, 0.f, 0.f, 0.f);
                if (n < N) w4 = *(const float4*)(Wd + (size_t)n * K + kc + k4);
                ushort4 u;
                u.x = f2bf(w4.x); u.y = f2bf(w4.y); u.z = f2bf(w4.z); u.w = f2bf(w4.w);
                *(ushort4*)&Bs[row][k4] = u;
            }
        } else {
#pragma unroll
            for (int it = 0; it < 16; ++it) {
                const int idx = it * 256 + tid;
                const int row = idx >> 5, kk = idx & 31;
                const int n = n0 + row;
                float v = 0.f;
                if (n < N && kk < K) v = Wd[(size_t)n * K + kk];
                Bs[row][kk] = f2bf(v);
            }
        }
        __syncthreads();
        bf16x8 af[4], bw[4];
#pragma unroll
        for (int f = 0; f < 4; ++f) {
            af[f] = *(const bf16x8*)&As[wm * 64 + f * 16 + (l & 15)][(l >> 4) * 8];
            bw[f] = *(const bf16x8*)&Bs[wn * 64 + f * 16 + (l & 15)][(l >> 4) * 8];
        }
#pragma unroll
        for (int fm = 0; fm < 4; ++fm)
#pragma unroll
            for (int fn = 0; fn < 4; ++fn)
                acc[fm][fn] = __builtin_amdgcn_mfma_f32_16x16x32_bf16(af[fm], bw[fn], acc[fm][fn], 0, 0, 0);
        __syncthreads();
    }
#pragma unroll
    for (int fn = 0; fn < 4; ++fn) {
        const int n = n0 + wn * 64 + fn * 16 + (l & 15);
        if (n < N) {
            const float bias = bihd[n] + bhhd[n];
#pragma unroll
            for (int fm = 0; fm < 4; ++fm) {
                const int mr = m0 + wm * 64 + fm * 16 + (l >> 4) * 4;
#pragma unroll
                for (int r = 0; r < 4; ++r)
                    st1(Xod + (size_t)(mr + r) * N + n, acc[fm][fn][r] + bias);
            }
        }
    }
}

// ---------------------------------------------------------------------------
// H=16 scan, k-split: lane l -> unit u = l&15, k-group g = l>>4 (4 k's each).
// 4 FMAs per gate per lane + shfl_xor(16,32) tree reduce; no LDS/barriers.
// ---------------------------------------------------------------------------
template<int PF, typename XT, typename AT>
__global__ __launch_bounds__(64, 1) void lstm_scan16(
    const XT* __restrict__ Xf, const XT* __restrict__ Xb_,
    AT* __restrict__ act, const float* __restrict__ whh,
    float* __restrict__ stats, float* __restrict__ state,
    int t0f, int tb_out, int CS, int first)
{
    const int l = threadIdx.x;
    const int dir = (blockIdx.x >= 64) ? 1 : 0;
    const int b = blockIdx.x & 63;
    const int u = l & 15;
    const int g4 = (l >> 4) * 4;

    float wi[4], wf_[4], wg[4], wo[4];
#pragma unroll
    for (int i = 0; i < 4; ++i) {
        wi[i]  = whh[(size_t)(dir * 64 +      u) * 16 + g4 + i];
        wf_[i] = whh[(size_t)(dir * 64 + 16 + u) * 16 + g4 + i];
        wg[i]  = whh[(size_t)(dir * 64 + 32 + u) * 16 + g4 + i];
        wo[i]  = whh[(size_t)(dir * 64 + 48 + u) * 16 + g4 + i];
    }

    const int sbase = (dir * 64 + b) * 32;
    float hv = 0.f, cc = 0.f, s1 = 0.f, s2 = 0.f;
    if (!first) { hv = state[sbase + u]; cc = state[sbase + 16 + u]; }

    const XT* Xd = (dir ? Xb_ : Xf) + (size_t)b * 64 + u;
    const size_t rstride = (size_t)64 * 64;
    float xw[PF][4];
#pragma unroll
    for (int p = 0; p < PF; ++p) {
        const size_t ro = (size_t)(dir ? (CS - 1 - p) : p) * rstride;
        xw[p][0] = ld1(Xd + ro);      xw[p][1] = ld1(Xd + ro + 16);
        xw[p][2] = ld1(Xd + ro + 32); xw[p][3] = ld1(Xd + ro + 48);
    }

    for (int tb = 0; tb < CS; tb += PF) {
#pragma unroll
        for (int p = 0; p < PF; ++p) {
            const int pstep = tb + p;
            const float h0 = shflf(hv, g4 + 0);
            const float h1 = shflf(hv, g4 + 1);
            const float h2 = shflf(hv, g4 + 2);
            const float h3 = shflf(hv, g4 + 3);
            float gi = h0 * wi[0]  + h1 * wi[1]  + h2 * wi[2]  + h3 * wi[3];
            float gf = h0 * wf_[0] + h1 * wf_[1] + h2 * wf_[2] + h3 * wf_[3];
            float gg = h0 * wg[0]  + h1 * wg[1]  + h2 * wg[2]  + h3 * wg[3];
            float go = h0 * wo[0]  + h1 * wo[1]  + h2 * wo[2]  + h3 * wo[3];
            gi += shflxf(gi, 16); gi += shflxf(gi, 32);
            gf += shflxf(gf, 16); gf += shflxf(gf, 32);
            gg += shflxf(gg, 16); gg += shflxf(gg, 32);
            go += shflxf(go, 16); go += shflxf(go, 32);
            gi += xw[p][0]; gf += xw[p][1]; gg += xw[p][2]; go += xw[p][3];
            if (pstep + PF < CS) {
                const size_t ro = (size_t)(dir ? (CS - 1 - (pstep + PF)) : (pstep + PF)) * rstride;
                xw[p][0] = ld1(Xd + ro);      xw[p][1] = ld1(Xd + ro + 16);
                xw[p][2] = ld1(Xd + ro + 32); xw[p][3] = ld1(Xd + ro + 48);
            }
            cc = sigm(gf) * cc + sigm(gi) * tanh_f(gg);
            hv = sigm(go) * tanh_f(cc);
            if (l < 16) {
                AT hq; st1(&hq, hv);
                const float hs = ld1(&hq);
                const int tt = dir ? (tb_out - pstep) : (t0f + pstep);
                act[((size_t)tt * B + b) * 32 + dir * 16 + l] = hq;
                s1 += hs; s2 += hs * hs;
            }
        }
    }
    if (l < 16) {
        state[sbase + l] = hv;
        state[sbase + 16 + l] = cc;
        atomicAdd(stats + dir * 16 + l, s1);
        atomicAdd(stats + 32 + dir * 16 + l, s2);
    }
}

// ---------------------------------------------------------------------------
// H=32 scan: ONE wave per chain. Lane j owns gate rows j (i/f) and 64+j (g/o).
// ---------------------------------------------------------------------------
template<int PF, typename XT, typename AT>
__global__ __launch_bounds__(64, 1) void lstm_scan32(
    const XT* __restrict__ Xf, const XT* __restrict__ Xb_,
    AT* __restrict__ act, const float* __restrict__ whh,
    float* __restrict__ stats, float* __restrict__ state,
    int t0f, int tb_out, int CS, int first)
{
    const int j = threadIdx.x;
    const int dir = (blockIdx.x >= 64) ? 1 : 0;
    const int b = blockIdx.x & 63;
    const int u = j & 31;

    float w0[32], w1[32];
#pragma unroll
    for (int k = 0; k < 32; ++k) {
        w0[k] = whh[(size_t)(dir * 128 + j) * 32 + k];
        w1[k] = whh[(size_t)(dir * 128 + 64 + j) * 32 + k];
    }

    const int sbase = (dir * 64 + b) * 64;
    float hv = 0.f, cc = 0.f, s1 = 0.f, s2 = 0.f;
    if (!first) { hv = state[sbase + u]; cc = state[sbase + 32 + u]; }

    const XT* Xd = (dir ? Xb_ : Xf) + (size_t)b * 128 + j;
    const size_t rstride = (size_t)64 * 128;
    float xwA[PF], xwB[PF];
#pragma unroll
    for (int p = 0; p < PF; ++p) {
        const size_t ro = (size_t)(dir ? (CS - 1 - p) : p) * rstride;
        xwA[p] = ld1(Xd + ro); xwB[p] = ld1(Xd + ro + 64);
    }

    for (int tb = 0; tb < CS; tb += PF) {
#pragma unroll
        for (int p = 0; p < PF; ++p) {
            const int pstep = tb + p;
            float gA = xwA[p], gB = xwB[p];
#pragma unroll
            for (int k = 0; k < 32; ++k) {
                const float s = shflf(hv, k);
                gA += s * w0[k]; gB += s * w1[k];
            }
            if (pstep + PF < CS) {
                const size_t ro = (size_t)(dir ? (CS - 1 - (pstep + PF)) : (pstep + PF)) * rstride;
                xwA[p] = ld1(Xd + ro); xwB[p] = ld1(Xd + ro + 64);
            }
            const float iv = shflf(gA, u);
            const float fv = shflf(gA, u + 32);
            const float gv = shflf(gB, u);
            const float ov = shflf(gB, u + 32);
            cc = sigm(fv) * cc + sigm(iv) * tanh_f(gv);
            hv = sigm(ov) * tanh_f(cc);
            if (j < 32) {
                AT hq; st1(&hq, hv);
                const float hs = ld1(&hq);
                const int tt = dir ? (tb_out - pstep) : (t0f + pstep);
                act[((size_t)tt * B + b) * 64 + dir * 32 + j] = hq;
                s1 += hs; s2 += hs * hs;
            }
        }
    }
    if (j < 32) {
        state[sbase + j] = hv;
        state[sbase + 32 + j] = cc;
        atomicAdd(stats + dir * 32 + j, s1);
        atomicAdd(stats + 64 + dir * 32 + j, s2);
    }
}

// ---------------------------------------------------------------------------
// H=64 scan, K-SPLIT + readlane broadcast (fixes round-11: VGPR=76 meant
// w[64] wasn't register-resident -> per-step reloads, 1610us/chunk).
// T=512: thread = (gate row j = tid&255, k-half kh = tid>>8); w[32]/thread
// (~50 VGPR). h kept in a register per lane (hreg = h[kh*32 + (l&31)]),
// refreshed by ONE stride-1 ds_read per step; dot uses v_readlane broadcasts
// (VALU) instead of per-wave LDS b128 broadcast reads.
// ---------------------------------------------------------------------------
template<int PF, typename XT, typename AT>
__global__ __launch_bounds__(512, 1) void lstm_scan64(
    const XT* __restrict__ Xf, const XT* __restrict__ Xb_,
    AT* __restrict__ act, const float* __restrict__ whh,
    float* __restrict__ stats, float* __restrict__ state,
    int t0f, int tb_out, int CS, int first)
{
    const int tid = threadIdx.x;
    const int j   = tid & 255;        // gate row (dir-local), rows: i|f|g|o x64
    const int kh  = tid >> 8;         // k-half: 0 -> k<32, 1 -> k>=32
    const int l   = tid & 63;         // lane in wave
    const int dir = (blockIdx.x >= 64) ? 1 : 0;
    const int b   = blockIdx.x & 63;

    __shared__ __align__(16) float h_lds[64];
    __shared__ __align__(16) float psum[2][256];

    float w[32];
#pragma unroll
    for (int k = 0; k < 32; ++k)
        w[k] = whh[((size_t)dir * 256 + j) * 64 + kh * 32 + k];

    const int sbase = (dir * 64 + b) * 128;
    float cc = 0.f, s1 = 0.f, s2 = 0.f;
    if (tid < 64) {
        float h0 = 0.f;
        if (!first) { h0 = state[sbase + tid]; cc = state[sbase + 64 + tid]; }
        h_lds[tid] = h0;
    }
    __syncthreads();
    float hreg = h_lds[kh * 32 + (l & 31)];   // lane k (k<32) holds h[kh*32+k]

    const XT* Xd = (dir ? Xb_ : Xf) + (size_t)b * 256 + j;
    const size_t rstride = (size_t)64 * 256;

    float xw[PF];
    if (kh == 0) {
#pragma unroll
        for (int p = 0; p < PF; ++p) {
            const int row = dir ? (CS - 1 - p) : p;
            xw[p] = ld1(Xd + (size_t)row * rstride);
        }
    }

    for (int tb = 0; tb < CS; tb += PF) {
#pragma unroll
        for (int p = 0; p < PF; ++p) {
            const int pstep = tb + p;
            float a0 = 0.f, a1 = 0.f, a2 = 0.f, a3 = 0.f;
#pragma unroll
            for (int k4 = 0; k4 < 8; ++k4) {
                a0 += bcastf(hreg, 4 * k4 + 0) * w[4 * k4 + 0];
                a1 += bcastf(hreg, 4 * k4 + 1) * w[4 * k4 + 1];
                a2 += bcastf(hreg, 4 * k4 + 2) * w[4 * k4 + 2];
                a3 += bcastf(hreg, 4 * k4 + 3) * w[4 * k4 + 3];
            }
            float partial = (a0 + a1) + (a2 + a3);
            if (kh == 0) {
                partial += xw[p];
                if (pstep + PF < CS) {
                    const int row = dir ? (CS - 1 - (pstep + PF)) : (pstep + PF);
                    xw[p] = ld1(Xd + (size_t)row * rstride);
                }
            }
            psum[kh][j] = partial;
            __syncthreads();
            if (tid < 64) {
                const int u = tid;
                const float gi = psum[0][u]       + psum[1][u];
                const float gf = psum[0][64 + u]  + psum[1][64 + u];
                const float gg = psum[0][128 + u] + psum[1][128 + u];
                const float go = psum[0][192 + u] + psum[1][192 + u];
                cc = sigm(gf) * cc + sigm(gi) * tanh_f(gg);
                const float hvv = sigm(go) * tanh_f(cc);
                h_lds[u] = hvv;
                AT hq; st1(&hq, hvv);
                const float hs = ld1(&hq);
                const int tt = dir ? (tb_out - pstep) : (t0f + pstep);
                act[((size_t)tt * B + b) * 128 + dir * 64 + u] = hq;
                s1 += hs; s2 += hs * hs;
            }
            __syncthreads();
            hreg = h_lds[kh * 32 + (l & 31)];
        }
    }
    if (tid < 64) {
        state[sbase + tid]      = h_lds[tid];
        state[sbase + 64 + tid] = cc;
        atomicAdd(stats + dir * 64 + tid, s1);
        atomicAdd(stats + 128 + dir * 64 + tid, s2);
    }
}

// ---------------------------------------------------------------------------
// H=128 scan, K-SPLIT + readlane broadcast. T=1024: thread = (row j=tid&511,
// k-half kh=tid>>9); w[64]/thread (~85 VGPR <= the 128 cap for 16-wave
// blocks). Round-11 version was LDS-pipe-bound (16 waves x 16 broadcast
// ds_read_b128/step ~= 3000 cy/step); hreg+readlane moves that to VALU.
// ---------------------------------------------------------------------------
template<int PF, typename XT, typename AT>
__global__ __launch_bounds__(1024, 1) void lstm_scan128(
    const XT* __restrict__ Xf, const XT* __restrict__ Xb_,
    AT* __restrict__ act, const float* __restrict__ whh,
    float* __restrict__ stats, float* __restrict__ state,
    int t0f, int tb_out, int CS, int first)
{
    const int tid = threadIdx.x;
    const int j   = tid & 511;        // gate row (dir-local)
    const int kh  = tid >> 9;         // k-half: 0 -> k<64, 1 -> k>=64
    const int l   = tid & 63;         // lane in wave
    const int dir = (blockIdx.x >= 64) ? 1 : 0;
    const int b   = blockIdx.x & 63;

    __shared__ __align__(16) float h_lds[128];
    __shared__ __align__(16) float psum[2][512];

    float w[64];
#pragma unroll
    for (int k = 0; k < 64; ++k)
        w[k] = whh[((size_t)dir * 512 + j) * 128 + kh * 64 + k];

    const int sbase = (dir * 64 + b) * 256;
    float cc = 0.f, s1 = 0.f, s2 = 0.f;
    if (tid < 128) {
        float h0 = 0.f;
        if (!first) { h0 = state[sbase + tid]; cc = state[sbase + 128 + tid]; }
        h_lds[tid] = h0;
    }
    __syncthreads();
    float hreg = h_lds[kh * 64 + l];   // lane k holds h[kh*64+k]

    const XT* Xd = (dir ? Xb_ : Xf) + (size_t)b * 512 + j;
    const size_t rstride = (size_t)64 * 512;

    float xw[PF];
    if (kh == 0) {
#pragma unroll
        for (int p = 0; p < PF; ++p) {
            const int row = dir ? (CS - 1 - p) : p;
            xw[p] = ld1(Xd + (size_t)row * rstride);
        }
    }

    for (int tb = 0; tb < CS; tb += PF) {
#pragma unroll
        for (int p = 0; p < PF; ++p) {
            const int pstep = tb + p;
            float a0 = 0.f, a1 = 0.f, a2 = 0.f, a3 = 0.f;
#pragma unroll
            for (int k4 = 0; k4 < 16; ++k4) {
                a0 += bcastf(hreg, 4 * k4 + 0) * w[4 * k4 + 0];
                a1 += bcastf(hreg, 4 * k4 + 1) * w[4 * k4 + 1];
                a2 += bcastf(hreg, 4 * k4 + 2) * w[4 * k4 + 2];
                a3 += bcastf(hreg, 4 * k4 + 3) * w[4 * k4 + 3];
            }
            float partial = (a0 + a1) + (a2 + a3);
            if (kh == 0) {
                partial += xw[p];
                if (pstep + PF < CS) {
                    const int row = dir ? (CS - 1 - (pstep + PF)) : (pstep + PF);
                    xw[p] = ld1(Xd + (size_t)row * rstride);
                }
            }
            psum[kh][j] = partial;
            __syncthreads();
            if (tid < 128) {
                const int u = tid;
                const float gi = psum[0][u]       + psum[1][u];
                const float gf = psum[0][128 + u] + psum[1][128 + u];
                const float gg = psum[0][256 + u] + psum[1][256 + u];
                const float go = psum[0][384 + u] + psum[1][384 + u];
                cc = sigm(gf) * cc + sigm(gi) * tanh_f(gg);
                const float hvv = sigm(go) * tanh_f(cc);
                h_lds[u] = hvv;
                AT hq; st1(&hq, hvv);
                const float hs = ld1(&hq);
                const int tt = dir ? (tb_out - pstep) : (t0f + pstep);
                act[((size_t)tt * B + b) * 256 + dir * 128 + u] = hq;
                s1 += hs; s2 += hs * hs;
            }
            __syncthreads();
            hreg = h_lds[kh * 64 + l];
        }
    }
    if (tid < 128) {
        state[sbase + tid]       = h_lds[tid];
        state[sbase + 128 + tid] = cc;
        atomicAdd(stats + dir * 128 + tid, s1);
        atomicAdd(stats + 256 + dir * 128 + tid, s2);
    }
}

// ---------------------------------------------------------------------------
// BN finalize: scg = gamma*rsqrt(var+eps), sb = beta - mean*scg
// ---------------------------------------------------------------------------
__global__ void bn_finalize(const float* __restrict__ sums, float* __restrict__ scg_sb,
                            const float* __restrict__ gamma, const float* __restrict__ beta,
                            int CO)
{
    const int c = threadIdx.x;
    if (c < CO) {
        const float inv  = 1.0f / (float)M;
        const float mean = sums[c] * inv;
        const float var  = fmaxf(sums[CO + c] * inv - mean * mean, 0.f);
        const float s    = gamma[c] * rsqrtf(var + 1e-5f);
        scg_sb[c]      = s;
        scg_sb[CO + c] = beta[c] - mean * s;
    }
}

// ---------------------------------------------------------------------------
// Final FC: out[b,s,j] = sum_c bn3(act[s,b,c]) * fc_w[j,c] + fc_b[j], j<11
// ---------------------------------------------------------------------------
template<typename AT>
__global__ __launch_bounds__(256) void fc_kernel(
    const AT* __restrict__ act, const float* __restrict__ scg_sb,
    const float* __restrict__ fc_w, const float* __restrict__ fc_b,
    float* __restrict__ out)
{
    __shared__ __align__(16) float a_s[32][264];
    __shared__ __align__(16) float w_s[11][264];
    const int tid = threadIdx.x;
    const int m0  = blockIdx.x * 32;
#pragma unroll
    for (int u = 0; u < 12; ++u) {
        int q = u * 256 + tid;
        int uu = q >> 8, c = q & 255;
        if (uu < 11) w_s[uu][c] = fc_w[uu * 256 + c];
    }
#pragma unroll
    for (int u = 0; u < 8; ++u) {
        int q = u * 256 + tid;
        int r = q >> 6, c4 = q & 63;
        const float4 a4 = ld4(act + (size_t)(m0 + r) * 256 + c4 * 4);
        const float4 g4 = *(const float4*)(scg_sb + c4 * 4);
        const float4 b4 = *(const float4*)(scg_sb + 256 + c4 * 4);
        float4 v;
        v.x = a4.x * g4.x + b4.x; v.y = a4.y * g4.y + b4.y;
        v.z = a4.z * g4.z + b4.z; v.w = a4.w * g4.w + b4.w;
        *(float4*)&a_s[r][c4 * 4] = v;
    }
    __syncthreads();
    const int r = tid >> 3, jj = tid & 7;
    const size_t m = (size_t)m0 + r;
    float* orow = out + ((m & 63) * S + (m >> 6)) * 11;
#pragma unroll
    for (int jv = 0; jv < 2; ++jv) {
        const int j = jj + jv * 8;
        if (j < 11) {
            float a0 = 0, a1 = 0, a2 = 0, a3 = 0;
#pragma unroll
            for (int c4 = 0; c4 < 64; ++c4) {
                const float4 av = *(const float4*)&a_s[r][c4 * 4];
                const float4 wv = *(const float4*)&w_s[j][c4 * 4];
                a0 += av.x * wv.x; a1 += av.y * wv.y;
                a2 += av.z * wv.z; a3 += av.w * wv.w;
            }
            orow[j] = (a0 + a1) + (a2 + a3) + fc_b[j];
        }
    }
}

// ---------------------------------------------------------------------------
// One bidirectional layer, time-chunked; ping-pong act buffers; fwd+bwd
// projections fused into ONE gemm launch (gridDim.z = 2).
// ---------------------------------------------------------------------------
template<int H, typename XT, typename AT, typename AIN>
static void run_layer(const AIN* A, const float* wih, const float* whh,
                      const float* bih, const float* bhh,
                      const float* scg_prev, AT* act_out,
                      float* stats_l, float* state, XT* Xbuf,
                      int K, int mode, int CS, hipStream_t stream)
{
    const int N4 = 4 * H, P = S / CS;
    const size_t half = (size_t)CS * 64 * N4;
    XT* Xf = Xbuf;
    XT* Xb = Xbuf + half;
    const dim3 gg(CS * 64 / 128, (N4 + 127) / 128, 2);
    for (int jc = 0; jc < P; ++jc) {
        gemm_mfma<XT, AIN><<<gg, 256, 0, stream>>>(
            A, wih, bih, bhh, scg_prev, Xf, K, N4, mode,
            jc * CS, S - (jc + 1) * CS, half);
        if constexpr (H == 16)
            lstm_scan16<4, XT, AT><<<128, 64, 0, stream>>>(
                Xf, Xb, act_out, whh, stats_l, state, jc * CS, S - 1 - jc * CS, CS, jc == 0);
        else if constexpr (H == 32)
            lstm_scan32<4, XT, AT><<<128, 64, 0, stream>>>(
                Xf, Xb, act_out, whh, stats_l, state, jc * CS, S - 1 - jc * CS, CS, jc == 0);
        else if constexpr (H == 64)
            lstm_scan64<4, XT, AT><<<128, 512, 0, stream>>>(
                Xf, Xb, act_out, whh, stats_l, state, jc * CS, S - 1 - jc * CS, CS, jc == 0);
        else
            lstm_scan128<4, XT, AT><<<128, 1024, 0, stream>>>(
                Xf, Xb, act_out, whh, stats_l, state, jc * CS, S - 1 - jc * CS, CS, jc == 0);
    }
}

// ---------------------------------------------------------------------------
// Orchestration (inputs order: x, then per layer wih/whh/bih/bhh/gamma/beta,
// then fc_w/fc_b). ws: stats[4096 f32] | state[32768 f32] | actA | actB | X.
// ---------------------------------------------------------------------------
template<typename XT, typename AT>
static void run_all(void* const* d_in, float* out, float* stats, float* state,
                    AT* actA, AT* actB, XT* Xbuf, const int* CS, hipStream_t stream)
{
    auto in = [&](int i) { return (const float*)d_in[i]; };
    zero_stats<<<16, 256, 0, stream>>>(stats);

    run_layer<16, XT, AT, float>((const float*)d_in[0], in(1), in(2), in(3), in(4),
                                 nullptr, actA, stats + 0, state, Xbuf, 7, 0, CS[0], stream);
    bn_finalize<<<1, 256, 0, stream>>>(stats + 0, stats + 512, in(5), in(6), 32);

    run_layer<32, XT, AT, AT>(actA, in(7), in(8), in(9), in(10),
                              stats + 512, actB, stats + 1024, state, Xbuf, 32, 1, CS[1], stream);
    bn_finalize<<<1, 256, 0, stream>>>(stats + 1024, stats + 1536, in(11), in(12), 64);

    run_layer<64, XT, AT, AT>(actB, in(13), in(14), in(15), in(16),
                              stats + 1536, actA, stats + 2048, state, Xbuf, 64, 1, CS[2], stream);
    bn_finalize<<<1, 256, 0, stream>>>(stats + 2048, stats + 2560, in(17), in(18), 128);

    run_layer<128, XT, AT, AT>(actA, in(19), in(20), in(21), in(22),
                               stats + 2560, actB, stats + 3072, state, Xbuf, 128, 1, CS[3], stream);
    bn_finalize<<<1, 256, 0, stream>>>(stats + 3072, stats + 3584, in(23), in(24), 256);

    fc_kernel<AT><<<M / 32, 256, 0, stream>>>(actB, stats + 3584, in(25), in(26), out);
}

// largest power-of-2 chunk CS in [64, 2048] whose 2-window X fits in xavail
static inline int fit_cs(size_t xavail, size_t bytes_per_step) {
    for (int cs = 2048; cs >= 64; cs >>= 1)
        if ((size_t)cs * bytes_per_step <= xavail) return cs;
    return 64;
}

extern "C" void kernel_launch(void* const* d_in, const int* in_sizes, int n_in,
                              void* d_out, int out_size, void* d_ws, size_t ws_size,
                              hipStream_t stream)
{
    (void)in_sizes; (void)n_in; (void)out_size;
    float* out = (float*)d_out;
    char* ws = (char*)d_ws;
    const size_t STB  = 16384;                 // stats: 4096 f32
    const size_t STT  = 131072;                // state: 2*64*2*128 f32
    const size_t HEAD = STB + STT;
    const size_t AAf  = (size_t)M * 128 * 4;   // actA fp32 (64 MiB)
    const size_t ABf  = (size_t)M * 256 * 4;   // actB fp32 (128 MiB)
    const size_t XF3  = (size_t)M * 1024 * 4;  // layer3 full fp32 X (537 MiB)
    const size_t XGOOD = (size_t)140 * 1024 * 1024;
    const int H8[4] = {128, 256, 512, 1024};   // both-dir X cols per layer

    float* stats = (float*)ws;
    float* state = (float*)(ws + STB);
    char*  bufs  = ws + HEAD;
    int CS[4];

    if (ws_size >= HEAD + AAf + ABf + XF3) {
        // Plan A: all fp32, full-length X (no chunk loops)
        float* actA = (float*)bufs;
        float* actB = (float*)(bufs + AAf);
        float* X    = (float*)(bufs + AAf + ABf);
        const size_t xavail = ws_size - HEAD - AAf - ABf;
        for (int l = 0; l < 4; ++l) CS[l] = fit_cs(xavail, (size_t)64 * H8[l] * 4);
        run_all<float, float>(d_in, out, stats, state, actA, actB, X, CS, stream);
    } else if (ws_size >= HEAD + AAf + ABf + XGOOD) {
        // Plan B: fp32 act, bf16 X, big chunks
        float* actA = (float*)bufs;
        float* actB = (float*)(bufs + AAf);
        __hip_bfloat16* X = (__hip_bfloat16*)(bufs + AAf + ABf);
        const size_t xavail = ws_size - HEAD - AAf - ABf;
        for (int l = 0; l < 4; ++l) CS[l] = fit_cs(xavail, (size_t)64 * H8[l] * 2);
        run_all<__hip_bfloat16, float>(d_in, out, stats, state, actA, actB, X, CS, stream);
    } else {
        // Plan C: bf16 act + bf16 X -- frees 96 MiB for X so chunks stay big
        __hip_bfloat16* actA = (__hip_bfloat16*)bufs;
        __hip_bfloat16* actB = (__hip_bfloat16*)(bufs + AAf / 2);
        __hip_bfloat16* X    = (__hip_bfloat16*)(bufs + AAf / 2 + ABf / 2);
        const size_t used = HEAD + AAf / 2 + ABf / 2;
        const size_t xavail = (ws_size > used) ? (ws_size - used) : 0;
        for (int l = 0; l < 4; ++l) CS[l] = fit_cs(xavail, (size_t)64 * H8[l] * 2);
        run_all<__hip_bfloat16, __hip_bfloat16>(d_in, out, stats, state, actA, actB, X, CS, stream);
    }
}